// Round 16
// baseline (155.752 us; speedup 1.0000x reference)
//
#include <hip/hip_runtime.h>
#include <math.h>

#define N_TOK 4096
#define DMODEL 512
#define NHEAD 4
#define HDIM 128
#define NBINS 32
#define BQ 128
#define BK 64
#define NSPLIT 4
#define KV_PER_SPLIT (N_TOK / NSPLIT)
#define QKSTR 1024   // row stride of fused Q|K buffer
#define MAXG 40

typedef __attribute__((ext_vector_type(8))) short bf16x8;
typedef __attribute__((ext_vector_type(4))) float f32x4;
typedef __attribute__((ext_vector_type(8))) unsigned short u16x8;
typedef __attribute__((ext_vector_type(4))) unsigned short u16x4;

__device__ __forceinline__ unsigned short f2bf(float x) {
    unsigned int u = __float_as_uint(x);
    u += 0x7FFFu + ((u >> 16) & 1u);   // round-to-nearest-even
    return (unsigned short)(u >> 16);
}
// native bf16 convert (compiler emits v_cvt_pk_bf16_f32, gfx950-native)
__device__ __forceinline__ unsigned short f2bf_hw(float x) {
    __bf16 b = (__bf16)x;
    union { __bf16 h; unsigned short u; } c;
    c.h = b;
    return c.u;
}
__device__ __forceinline__ float bf2f(unsigned short u) {
    return __uint_as_float(((unsigned int)u) << 16);
}

// ---------------------------------------------------------------- weights fp32 -> bf16 (5x 512x512)
__global__ __launch_bounds__(256) void wconv5(const float* __restrict__ w0, const float* __restrict__ w1,
                                              const float* __restrict__ w2, const float* __restrict__ w3,
                                              const float* __restrict__ w4,
                                              unsigned short* __restrict__ dstbase) {
    const float* srcs[5] = {w0, w1, w2, w3, w4};
    const float* src = srcs[blockIdx.y];
    unsigned short* dst = dstbase + (size_t)blockIdx.y * DMODEL * DMODEL;
    int idx = (blockIdx.x * 256 + threadIdx.x) * 4;
    float4 v = *(const float4*)&src[idx];
    u16x4 r;
    r[0] = f2bf(v.x); r[1] = f2bf(v.y); r[2] = f2bf(v.z); r[3] = f2bf(v.w);
    *(u16x4*)&dst[idx] = r;
}

// ---------------------------------------------------------------- PE contribution tables (f32)
// p in [0,40): contribR[p][c] = sum_j rpe_p[j] * pos_w[c][j]        (j < 256)
// p in [40,80): contribC[p-40][c] = sum_j cpe_p[j] * pos_w[c][256+j]
// Only 40 distinct row/col positions exist (MAX_GRID=40) -> the whole pe@pos_w^T GEMM
// collapses to 80 x 512 table entries (21 MFLOP, f32-exact).
__global__ __launch_bounds__(256) void pos_contrib(const float* __restrict__ pos_w,
                                                   float* __restrict__ contrib) {
    const int p = blockIdx.x;          // 0..79
    const int t = threadIdx.x;
    const bool isRow = p < MAXG;
    const float pos = (float)(isRow ? p : p - MAXG);
    __shared__ float pe[256];
    {
        int k = t >> 1;
        float freq = expf(-0.035977892078032f * (float)(2 * k));
        float ang = pos * freq;
        pe[t] = (t & 1) ? cosf(ang) : sinf(ang);
    }
    __syncthreads();
    const int jofs = isRow ? 0 : 256;
#pragma unroll
    for (int cc = 0; cc < 2; ++cc) {
        int c = t + cc * 256;
        const float* wrow = &pos_w[(size_t)c * DMODEL + jofs];
        float acc = 0.f;
        for (int j = 0; j < 256; j += 4) {
            float4 w4 = *(const float4*)&wrow[j];
            acc += pe[j] * w4.x + pe[j + 1] * w4.y + pe[j + 2] * w4.z + pe[j + 3] * w4.w;
        }
        contrib[(size_t)p * DMODEL + c] = acc;
    }
}

// ---------------------------------------------------------------- h_pos = vh + contribR[row] + contribC[col]; also vh -> bf16
__global__ __launch_bounds__(256) void hpos_kernel(const int* __restrict__ rows,
                                                   const int* __restrict__ cols,
                                                   const float* __restrict__ vh,
                                                   const float* __restrict__ contrib,
                                                   unsigned short* __restrict__ vh_bf,
                                                   unsigned short* __restrict__ hpos_bf) {
    const int n = blockIdx.x, t = threadIdx.x;
    const float* rc = &contrib[(size_t)rows[n] * DMODEL];
    const float* cc = &contrib[(size_t)(MAXG + cols[n]) * DMODEL];
    const size_t base = (size_t)n * DMODEL;
    const int c = t * 2;
    float2 v = *(const float2*)&vh[base + c];
    vh_bf[base + c]     = f2bf(v.x);
    vh_bf[base + c + 1] = f2bf(v.y);
    float2 r = *(const float2*)&rc[c];
    float2 cl = *(const float2*)&cc[c];
    hpos_bf[base + c]     = f2bf(v.x + r.x + cl.x);
    hpos_bf[base + c + 1] = f2bf(v.y + r.y + cl.y);
}

// ---------------------------------------------------------------- MFMA GEMM: C[M][N] = A[M][K] @ B[N][K]^T
// ROUND-14 PROVEN: 64x128 tile, reg-prefetch staging, 4 waves 2x2 (wave tile 32x64).
// Per-col scale: cols<512 -> scaleA else scaleB.
template <bool ADD, bool BF16OUT>
__global__ __launch_bounds__(256) void gemm_mfma(const unsigned short* __restrict__ A,
                                                 const unsigned short* __restrict__ B,
                                                 const float* __restrict__ addv,
                                                 void* __restrict__ Cv,
                                                 int M, int N, int K,
                                                 float scaleA, float scaleB) {
    const int n0 = blockIdx.x * 64;
    const int j0 = blockIdx.y * 128;
    __shared__ unsigned short As[64][72];
    __shared__ unsigned short Bs[128][72];
    const int t    = threadIdx.x;
    const int wid  = t >> 6;
    const int wr   = wid >> 1, wc = wid & 1;
    const int lane = t & 63;
    const int lg   = lane >> 4, li = lane & 15;
    const int str  = t >> 3;          // 0..31
    const int sc   = (t & 7) * 8;

    f32x4 acc[2][4];
#pragma unroll
    for (int i = 0; i < 2; ++i)
#pragma unroll
        for (int j = 0; j < 4; ++j) acc[i][j] = (f32x4){0.f, 0.f, 0.f, 0.f};

    u16x8 areg[2], breg[4];
#pragma unroll
    for (int i = 0; i < 2; ++i)
        areg[i] = *(const u16x8*)&A[(size_t)(n0 + str + i * 32) * K + sc];
#pragma unroll
    for (int i = 0; i < 4; ++i)
        breg[i] = *(const u16x8*)&B[(size_t)(j0 + str + i * 32) * K + sc];

    for (int k0 = 0; k0 < K; k0 += 64) {
        __syncthreads();
#pragma unroll
        for (int i = 0; i < 2; ++i) *(u16x8*)&As[str + i * 32][sc] = areg[i];
#pragma unroll
        for (int i = 0; i < 4; ++i) *(u16x8*)&Bs[str + i * 32][sc] = breg[i];
        __syncthreads();
        if (k0 + 64 < K) {
#pragma unroll
            for (int i = 0; i < 2; ++i)
                areg[i] = *(const u16x8*)&A[(size_t)(n0 + str + i * 32) * K + k0 + 64 + sc];
#pragma unroll
            for (int i = 0; i < 4; ++i)
                breg[i] = *(const u16x8*)&B[(size_t)(j0 + str + i * 32) * K + k0 + 64 + sc];
        }
        __builtin_amdgcn_s_setprio(1);
#pragma unroll
        for (int kc = 0; kc < 2; ++kc) {
            bf16x8 af[2], bfr[4];
#pragma unroll
            for (int mf = 0; mf < 2; ++mf)
                af[mf] = *(const bf16x8*)&As[wr * 32 + mf * 16 + li][kc * 32 + lg * 8];
#pragma unroll
            for (int nf = 0; nf < 4; ++nf)
                bfr[nf] = *(const bf16x8*)&Bs[wc * 64 + nf * 16 + li][kc * 32 + lg * 8];
#pragma unroll
            for (int mf = 0; mf < 2; ++mf)
#pragma unroll
                for (int nf = 0; nf < 4; ++nf)
                    acc[mf][nf] = __builtin_amdgcn_mfma_f32_16x16x32_bf16(af[mf], bfr[nf], acc[mf][nf], 0, 0, 0);
        }
        __builtin_amdgcn_s_setprio(0);
    }
    const float scl = (j0 < 512) ? scaleA : scaleB;
#pragma unroll
    for (int mf = 0; mf < 2; ++mf) {
#pragma unroll
        for (int r = 0; r < 4; ++r) {
            const int row = n0 + wr * 32 + mf * 16 + lg * 4 + r;
#pragma unroll
            for (int nf = 0; nf < 4; ++nf) {
                const int col = j0 + wc * 64 + nf * 16 + li;
                float v = acc[mf][nf][r] * scl;
                if (ADD) v += addv[(size_t)row * N + col];
                if (BF16OUT) ((unsigned short*)Cv)[(size_t)row * N + col] = f2bf(v);
                else         ((float*)Cv)[(size_t)row * N + col] = v;
            }
        }
    }
}

// ---------------------------------------------------------------- MFMA flash attention, K-split x4
// ROUND-14 PROVEN STRUCTURE (unchanged): BQ=128, 8 waves x 16 q-rows; swapped QK^T;
// defer-max (THR=8); XOR-swizzled K/V LDS; launch_bounds(512,2).
__global__ __launch_bounds__(512, 2) void attn_mfma(const unsigned short* __restrict__ Qb,
                                                    const unsigned short* __restrict__ Kb,
                                                    const unsigned short* __restrict__ Vtb,
                                                    const int* __restrict__ prows,
                                                    const int* __restrict__ pcols,
                                                    const float* __restrict__ dist_bias,
                                                    unsigned short* __restrict__ Opart,
                                                    float* __restrict__ Mp,
                                                    float* __restrict__ Lp) {
    const int h  = blockIdx.y;
    const int n0 = blockIdx.x * BQ;
    const int sp = blockIdx.z;
    __shared__ unsigned short Ks[BK * HDIM];        // [64][128] XOR-swizzled
    __shared__ unsigned short Vts[HDIM * BK];       // [128][64] XOR-swizzled
    __shared__ unsigned short Ps[BQ][68];           // +4 pad
    __shared__ unsigned short biasTb[3043];
    __shared__ int krs[BK], kcs[BK];

    const int t    = threadIdx.x;
    const int lane = t & 63;
    const int lg   = lane >> 4;
    const int li   = lane & 15;
    const int qbase = (t >> 6) * 16;   // 8 waves x 16 q-rows

    for (int idx = t; idx < 3043; idx += 512) {
        float d  = sqrtf((float)idx);
        int bin  = (int)(log1pf(d) * (31.0f / 4.0529789877f));
        bin = bin > 31 ? 31 : bin;
        biasTb[idx] = f2bf(dist_bias[h * NBINS + bin]);
    }

    bf16x8 qf[4];
    {
        const unsigned short* qptr = &Qb[(size_t)(n0 + qbase + li) * QKSTR + h * HDIM];
#pragma unroll
        for (int kc = 0; kc < 4; ++kc)
            qf[kc] = *(const bf16x8*)&qptr[kc * 32 + lg * 8];
    }
    const int qrL = prows[n0 + qbase + li];
    const int qcL = pcols[n0 + qbase + li];

    float m_ = -1e30f;
    float l_ = 0.f;
    f32x4 accO[8];
#pragma unroll
    for (int dt = 0; dt < 8; ++dt) accO[dt] = (f32x4){0.f, 0.f, 0.f, 0.f};

    // staging (512 threads): K rows ktr,ktr+32; V rows vtr,vtr+64
    u16x8 kreg[2], vreg[2];
    int krreg = 0, kcreg = 0;
    const int ktr = t >> 4, kch = (t & 15) * 8;   // ktr 0..31
    const int vtr = t >> 3, vch = (t & 7) * 8;    // vtr 0..63

    const int kwofs0 = (ktr * 128 + kch) * 2;
    const int vwofs0 = (vtr * 64 + vch) * 2;

    int m0 = sp * KV_PER_SPLIT;
    {
#pragma unroll
        for (int i = 0; i < 2; ++i)
            kreg[i] = *(const u16x8*)&Kb[(size_t)(m0 + ktr + i * 32) * QKSTR + h * HDIM + kch];
#pragma unroll
        for (int i = 0; i < 2; ++i)
            vreg[i] = *(const u16x8*)&Vtb[(size_t)(h * HDIM + vtr + i * 64) * N_TOK + m0 + vch];
        if (t < BK) { krreg = prows[m0 + t]; kcreg = pcols[m0 + t]; }
    }

    for (int kb = 0; kb < KV_PER_SPLIT / BK; ++kb, m0 += BK) {
        __syncthreads();
#pragma unroll
        for (int i = 0; i < 2; ++i) {
            int ofs = (kwofs0 + i * 32 * 256) ^ ((ktr & 7) << 4);
            *(u16x8*)((char*)Ks + ofs) = kreg[i];
        }
#pragma unroll
        for (int i = 0; i < 2; ++i) {
            int ofs = (vwofs0 + i * 64 * 128) ^ ((vtr & 7) << 4);
            *(u16x8*)((char*)Vts + ofs) = vreg[i];
        }
        if (t < BK) { krs[t] = krreg; kcs[t] = kcreg; }
        __syncthreads();

        if (kb + 1 < KV_PER_SPLIT / BK) {
            const int m1 = m0 + BK;
#pragma unroll
            for (int i = 0; i < 2; ++i)
                kreg[i] = *(const u16x8*)&Kb[(size_t)(m1 + ktr + i * 32) * QKSTR + h * HDIM + kch];
#pragma unroll
            for (int i = 0; i < 2; ++i)
                vreg[i] = *(const u16x8*)&Vtb[(size_t)(h * HDIM + vtr + i * 64) * N_TOK + m1 + vch];
            if (t < BK) { krreg = prows[m1 + t]; kcreg = pcols[m1 + t]; }
        }

        // ---- S^T = K Q^T : lane gets P[q=li][k = jt*16 + lg*4 + r]
        f32x4 s[4];
        __builtin_amdgcn_s_setprio(1);
#pragma unroll
        for (int jt = 0; jt < 4; ++jt) {
            f32x4 acc = {0.f, 0.f, 0.f, 0.f};
#pragma unroll
            for (int kc = 0; kc < 4; ++kc) {
                int ofs = (((jt * 16 + li) * 128 + kc * 32 + lg * 8) * 2) ^ ((li & 7) << 4);
                bf16x8 kf = *(const bf16x8*)((const char*)Ks + ofs);
                acc = __builtin_amdgcn_mfma_f32_16x16x32_bf16(kf, qf[kc], acc, 0, 0, 0);
            }
            s[jt] = acc;
        }
        __builtin_amdgcn_s_setprio(0);

        // ---- bias
        float p[4][4];
#pragma unroll
        for (int jt = 0; jt < 4; ++jt) {
#pragma unroll
            for (int r = 0; r < 4; ++r) {
                int k  = jt * 16 + lg * 4 + r;
                int dr = qrL - krs[k], dc = qcL - kcs[k];
                p[jt][r] = s[jt][r] + bf2f(biasTb[dr * dr + dc * dc]);
            }
        }

        // ---- row max: tree + 2 shfl
        float t0 = fmaxf(fmaxf(p[0][0], p[0][1]), fmaxf(p[0][2], p[0][3]));
        float t1 = fmaxf(fmaxf(p[1][0], p[1][1]), fmaxf(p[1][2], p[1][3]));
        float t2 = fmaxf(fmaxf(p[2][0], p[2][1]), fmaxf(p[2][2], p[2][3]));
        float t3 = fmaxf(fmaxf(p[3][0], p[3][1]), fmaxf(p[3][2], p[3][3]));
        float pmax = fmaxf(fmaxf(t0, t1), fmaxf(t2, t3));
        pmax = fmaxf(pmax, __shfl_xor(pmax, 16));
        pmax = fmaxf(pmax, __shfl_xor(pmax, 32));

        // ---- defer-max (THR=8)
        if (!__all(pmax <= m_ + 8.0f)) {
            float mnew  = fmaxf(m_, pmax);
            float alpha = __expf(m_ - mnew);
            m_ = mnew;
            l_ *= alpha;
            float aq[4];
#pragma unroll
            for (int r = 0; r < 4; ++r)
                aq[r] = __shfl(alpha, (lane & 48) | (lg * 4 + r));
#pragma unroll
            for (int dt = 0; dt < 8; ++dt)
#pragma unroll
                for (int r = 0; r < 4; ++r) accO[dt][r] *= aq[r];
        }

        // ---- exp + row sum
        float rs = 0.f;
#pragma unroll
        for (int jt = 0; jt < 4; ++jt)
#pragma unroll
            for (int r = 0; r < 4; ++r) { p[jt][r] = __expf(p[jt][r] - m_); rs += p[jt][r]; }
        rs += __shfl_xor(rs, 16);
        rs += __shfl_xor(rs, 32);
        l_ += rs;

        // ---- P -> LDS (native bf16 cvt)
#pragma unroll
        for (int jt = 0; jt < 4; ++jt) {
            u16x4 w;
#pragma unroll
            for (int r = 0; r < 4; ++r) w[r] = f2bf_hw(p[jt][r]);
            *(u16x4*)&Ps[qbase + li][jt * 16 + lg * 4] = w;
        }

        // ---- O += P V
        bf16x8 pf0 = *(const bf16x8*)&Ps[qbase + li][lg * 8];
        bf16x8 pf1 = *(const bf16x8*)&Ps[qbase + li][32 + lg * 8];
        __builtin_amdgcn_s_setprio(1);
#pragma unroll
        for (int dt = 0; dt < 8; ++dt) {
            int ofs0 = (((dt * 16 + li) * 64 + lg * 8) * 2) ^ ((li & 7) << 4);
            bf16x8 vf0 = *(const bf16x8*)((const char*)Vts + ofs0);
            bf16x8 vf1 = *(const bf16x8*)((const char*)Vts + (ofs0 ^ 64));
            accO[dt] = __builtin_amdgcn_mfma_f32_16x16x32_bf16(pf0, vf0, accO[dt], 0, 0, 0);
            accO[dt] = __builtin_amdgcn_mfma_f32_16x16x32_bf16(pf1, vf1, accO[dt], 0, 0, 0);
        }
        __builtin_amdgcn_s_setprio(0);
    }

    // ---- epilogue
    float linv[4];
#pragma unroll
    for (int r = 0; r < 4; ++r)
        linv[r] = __shfl(l_, (lane & 48) | (lg * 4 + r));
#pragma unroll
    for (int r = 0; r < 4; ++r) {
        float inv = 1.0f / linv[r];
        int row = n0 + qbase + lg * 4 + r;
#pragma unroll
        for (int dt = 0; dt < 8; ++dt)
            Opart[(size_t)sp * N_TOK * DMODEL + (size_t)row * DMODEL + h * HDIM + dt * 16 + li] =
                f2bf(accO[dt][r] * inv);
    }
    if (lane < 16) {
        int row = n0 + qbase + lane;
        Mp[((size_t)sp * NHEAD + h) * N_TOK + row] = m_;
        Lp[((size_t)sp * NHEAD + h) * N_TOK + row] = l_;
    }
}

// ---------------------------------------------------------------- combine 4 K-split partials -> bf16
__global__ __launch_bounds__(256) void combine_kernel(const unsigned short* __restrict__ Opart,
                                                      const float* __restrict__ Mp,
                                                      const float* __restrict__ Lp,
                                                      unsigned short* __restrict__ outbf) {
    int n = blockIdx.x, t = threadIdx.x;
#pragma unroll
    for (int d0 = t; d0 < DMODEL; d0 += 256) {
        int h = d0 >> 7;
        float mm[NSPLIT], ll[NSPLIT];
        float m = -1e30f;
#pragma unroll
        for (int s = 0; s < NSPLIT; ++s) {
            mm[s] = Mp[((size_t)s * NHEAD + h) * N_TOK + n];
            ll[s] = Lp[((size_t)s * NHEAD + h) * N_TOK + n];
            m = fmaxf(m, mm[s]);
        }
        float acc = 0.f, lsum = 0.f;
#pragma unroll
        for (int s = 0; s < NSPLIT; ++s) {
            float a = __expf(mm[s] - m) * ll[s];
            lsum += a;
            acc += a * bf2f(Opart[(size_t)s * N_TOK * DMODEL + (size_t)n * DMODEL + d0]);
        }
        outbf[(size_t)n * DMODEL + d0] = f2bf(acc / lsum);
    }
}

// ---------------------------------------------------------------- LN + gated residual
__global__ __launch_bounds__(256) void final_kernel(const float* __restrict__ o,
                                                    const float* __restrict__ vh,
                                                    const float* __restrict__ lnw,
                                                    const float* __restrict__ lnb,
                                                    const float* __restrict__ gparam,
                                                    float* __restrict__ out) {
    int n = blockIdx.x, t = threadIdx.x;
    size_t base = (size_t)n * DMODEL;
    float x0 = o[base + t], x1 = o[base + t + 256];
    __shared__ float red[4];
    float v = x0 + x1;
#pragma unroll
    for (int off = 32; off > 0; off >>= 1) v += __shfl_down(v, off, 64);
    if ((t & 63) == 0) red[t >> 6] = v;
    __syncthreads();
    float mu = (red[0] + red[1] + red[2] + red[3]) * (1.0f / 512.0f);
    __syncthreads();
    float d0 = x0 - mu, d1 = x1 - mu;
    v = d0 * d0 + d1 * d1;
#pragma unroll
    for (int off = 32; off > 0; off >>= 1) v += __shfl_down(v, off, 64);
    if ((t & 63) == 0) red[t >> 6] = v;
    __syncthreads();
    float var  = (red[0] + red[1] + red[2] + red[3]) * (1.0f / 512.0f);
    float rstd = rsqrtf(var + 1e-5f);
    float gamma = log1pf(expf(gparam[0]));
    out[base + t]       = vh[base + t]       + gamma * (d0 * rstd * lnw[t]       + lnb[t]);
    out[base + t + 256] = vh[base + t + 256] + gamma * (d1 * rstd * lnw[t + 256] + lnb[t + 256]);
}

// ---------------------------------------------------------------- launch
extern "C" void kernel_launch(void* const* d_in, const int* in_sizes, int n_in,
                              void* d_out, int out_size, void* d_ws, size_t ws_size,
                              hipStream_t stream) {
    const float* vision_h  = (const float*)d_in[0];
    const int*   prows     = (const int*)d_in[1];
    const int*   pcols     = (const int*)d_in[2];
    const float* pos_w     = (const float*)d_in[3];
    const float* q_w       = (const float*)d_in[4];
    const float* k_w       = (const float*)d_in[5];
    const float* v_w       = (const float*)d_in[6];
    const float* out_w     = (const float*)d_in[7];
    const float* dist_bias = (const float*)d_in[8];
    const float* gamma_p   = (const float*)d_in[9];
    const float* ln_w      = (const float*)d_in[10];
    const float* ln_b      = (const float*)d_in[11];
    float* out = (float*)d_out;
    char* base = (char*)d_ws;

    const size_t MB = 1024 * 1024;
    unsigned short* vh_bf   = (unsigned short*)(base + 4  * MB);
    unsigned short* hpos_bf = (unsigned short*)(base + 8  * MB);
    unsigned short* Opart   = (unsigned short*)(base + 0);        // 16MB, after vh/hpos dead
    float*          ob      = (float*)(base + 0);                 // 8MB, after Opart dead
    unsigned short* QKb     = (unsigned short*)(base + 16 * MB);  // 8MB fused Q|K [4096][1024]
    unsigned short* Vtb     = (unsigned short*)(base + 24 * MB);  // 4MB
    unsigned short* attn_bf = (unsigned short*)(base + 28 * MB);  // 4MB
    float*          Mp      = (float*)(base + 32 * MB);           // 256KB
    float*          Lp      = (float*)(base + 32 * MB + 262144);  // 256KB
    unsigned short* wbf     = (unsigned short*)(base + 32 * MB + 524288);  // 2.5MB -> ends 35MB
    float*          contrib = (float*)(base + 35 * MB);           // 80x512 f32 = 160KB

    unsigned short* w_pos = wbf;                        // unused now (kept for layout)
    unsigned short* w_q   = wbf + 1 * DMODEL * DMODEL;  // w_q||w_k contiguous -> fused B [1024][512]
    unsigned short* w_v   = wbf + 3 * DMODEL * DMODEL;
    unsigned short* w_o   = wbf + 4 * DMODEL * DMODEL;
    (void)w_pos;

    const float qscale = 0.08838834764831845f;  // 1/sqrt(128)

    wconv5<<<dim3(256, 5), 256, 0, stream>>>(pos_w, q_w, k_w, v_w, out_w, wbf);
    pos_contrib<<<2 * MAXG, 256, 0, stream>>>(pos_w, contrib);
    hpos_kernel<<<N_TOK, 256, 0, stream>>>(prows, pcols, vision_h, contrib, vh_bf, hpos_bf);
    // fused [Q|K] = h_pos @ [w_q;w_k]^T  (cols<512 scaled by qscale)
    gemm_mfma<false, true ><<<dim3(64, 8), 256, 0, stream>>>(hpos_bf, w_q, nullptr, QKb,
                                                             N_TOK, 1024, DMODEL, qscale, 1.0f);
    // Vt = v_w @ vision_h^T
    gemm_mfma<false, true ><<<dim3(8, 32), 256, 0, stream>>>(w_v, vh_bf, nullptr, Vtb,
                                                             DMODEL, N_TOK, DMODEL, 1.0f, 1.0f);
    attn_mfma<<<dim3(N_TOK / BQ, NHEAD, NSPLIT), 512, 0, stream>>>(QKb, QKb + 512, Vtb, prows, pcols,
                                                                   dist_bias, Opart, Mp, Lp);
    combine_kernel<<<N_TOK, 256, 0, stream>>>(Opart, Mp, Lp, attn_bf);
    gemm_mfma<false, false><<<dim3(64, 4), 256, 0, stream>>>(attn_bf, w_o, nullptr, ob,
                                                             N_TOK, DMODEL, DMODEL, 1.0f, 1.0f);
    final_kernel<<<N_TOK, 256, 0, stream>>>(ob, vision_h, ln_w, ln_b, gamma_p, out);
}

// Round 17
// 143.105 us; speedup vs baseline: 1.0884x; 1.0884x over previous
//
#include <hip/hip_runtime.h>
#include <math.h>

#define N_TOK 4096
#define DMODEL 512
#define NHEAD 4
#define HDIM 128
#define NBINS 32
#define BQ 128
#define BK 64
#define NSPLIT 4
#define KV_PER_SPLIT (N_TOK / NSPLIT)
#define QKSTR 1024   // row stride of fused Q|K buffer
#define MAXG 40

typedef __attribute__((ext_vector_type(8))) short bf16x8;
typedef __attribute__((ext_vector_type(4))) float f32x4;
typedef __attribute__((ext_vector_type(8))) unsigned short u16x8;
typedef __attribute__((ext_vector_type(4))) unsigned short u16x4;

__device__ __forceinline__ unsigned short f2bf(float x) {
    unsigned int u = __float_as_uint(x);
    u += 0x7FFFu + ((u >> 16) & 1u);   // round-to-nearest-even
    return (unsigned short)(u >> 16);
}
// native bf16 convert (compiler emits v_cvt_pk_bf16_f32, gfx950-native)
__device__ __forceinline__ unsigned short f2bf_hw(float x) {
    __bf16 b = (__bf16)x;
    union { __bf16 h; unsigned short u; } c;
    c.h = b;
    return c.u;
}
__device__ __forceinline__ float bf2f(unsigned short u) {
    return __uint_as_float(((unsigned int)u) << 16);
}

// ---------------------------------------------------------------- fused prep:
// blocks [0,1280): 5 weights fp32->bf16 ; blocks [1280,1600): PE contribution tables.
// Table: p in [0,40) rows / [40,80) cols; contrib[p][c] = sum_j pe_p[j] * pos_w[c][jofs+j].
// Only 40 distinct row/col positions (MAX_GRID=40) -> pe@pos_w^T collapses to 80x512 f32 table.
__global__ __launch_bounds__(256) void prep2_kernel(const float* __restrict__ w0, const float* __restrict__ w1,
                                                    const float* __restrict__ w2, const float* __restrict__ w3,
                                                    const float* __restrict__ w4,
                                                    const float* __restrict__ pos_w,
                                                    unsigned short* __restrict__ wbf,
                                                    float* __restrict__ contrib) {
    const int bid = blockIdx.x, t = threadIdx.x;
    if (bid < 1280) {
        const float* srcs[5] = {w0, w1, w2, w3, w4};
        const float* src = srcs[bid >> 8];
        unsigned short* dst = wbf + (size_t)(bid >> 8) * DMODEL * DMODEL;
        int idx = ((bid & 255) * 256 + t) * 4;
        float4 v = *(const float4*)&src[idx];
        u16x4 r;
        r[0] = f2bf(v.x); r[1] = f2bf(v.y); r[2] = f2bf(v.z); r[3] = f2bf(v.w);
        *(u16x4*)&dst[idx] = r;
    } else {
        const int q  = bid - 1280;       // 0..319
        const int p  = q >> 2;           // 0..79
        const int cy = q & 3;            // 128-col slice
        const bool isRow = p < MAXG;
        const float pos = (float)(isRow ? p : p - MAXG);
        __shared__ float pe[256];
        {
            int k = t >> 1;
            float freq = expf(-0.035977892078032f * (float)(2 * k));
            float ang = pos * freq;
            pe[t] = (t & 1) ? cosf(ang) : sinf(ang);
        }
        __syncthreads();
        const int jofs = isRow ? 0 : 256;
        const int col  = cy * 128 + (t >> 1);
        const int half = t & 1;
        const float* wrow = &pos_w[(size_t)col * DMODEL + jofs + half * 128];
        const float* peh  = &pe[half * 128];
        float acc = 0.f;
        for (int j = 0; j < 128; j += 4) {
            float4 w4 = *(const float4*)&wrow[j];
            acc += peh[j] * w4.x + peh[j + 1] * w4.y + peh[j + 2] * w4.z + peh[j + 3] * w4.w;
        }
        acc += __shfl_xor(acc, 1);
        if (half == 0) contrib[(size_t)p * DMODEL + col] = acc;
    }
}

// ---------------------------------------------------------------- h_pos = vh + contribR[row] + contribC[col]; also vh -> bf16
__global__ __launch_bounds__(256) void hpos_kernel(const int* __restrict__ rows,
                                                   const int* __restrict__ cols,
                                                   const float* __restrict__ vh,
                                                   const float* __restrict__ contrib,
                                                   unsigned short* __restrict__ vh_bf,
                                                   unsigned short* __restrict__ hpos_bf) {
    const int n = blockIdx.x, t = threadIdx.x;
    const float* rc = &contrib[(size_t)rows[n] * DMODEL];
    const float* cc = &contrib[(size_t)(MAXG + cols[n]) * DMODEL];
    const size_t base = (size_t)n * DMODEL;
    const int c = t * 2;
    float2 v = *(const float2*)&vh[base + c];
    vh_bf[base + c]     = f2bf(v.x);
    vh_bf[base + c + 1] = f2bf(v.y);
    float2 r = *(const float2*)&rc[c];
    float2 cl = *(const float2*)&cc[c];
    hpos_bf[base + c]     = f2bf(v.x + r.x + cl.x);
    hpos_bf[base + c + 1] = f2bf(v.y + r.y + cl.y);
}

// ---------------------------------------------------------------- MFMA GEMM: C[M][N] = A[M][K] @ B[N][K]^T
// ROUND-14 PROVEN: 64x128 tile, reg-prefetch staging, 4 waves 2x2 (wave tile 32x64).
// Per-col scale: cols<512 -> scaleA else scaleB.
template <bool ADD, bool BF16OUT>
__global__ __launch_bounds__(256) void gemm_mfma(const unsigned short* __restrict__ A,
                                                 const unsigned short* __restrict__ B,
                                                 const float* __restrict__ addv,
                                                 void* __restrict__ Cv,
                                                 int M, int N, int K,
                                                 float scaleA, float scaleB) {
    const int n0 = blockIdx.x * 64;
    const int j0 = blockIdx.y * 128;
    __shared__ unsigned short As[64][72];
    __shared__ unsigned short Bs[128][72];
    const int t    = threadIdx.x;
    const int wid  = t >> 6;
    const int wr   = wid >> 1, wc = wid & 1;
    const int lane = t & 63;
    const int lg   = lane >> 4, li = lane & 15;
    const int str  = t >> 3;          // 0..31
    const int sc   = (t & 7) * 8;

    f32x4 acc[2][4];
#pragma unroll
    for (int i = 0; i < 2; ++i)
#pragma unroll
        for (int j = 0; j < 4; ++j) acc[i][j] = (f32x4){0.f, 0.f, 0.f, 0.f};

    u16x8 areg[2], breg[4];
#pragma unroll
    for (int i = 0; i < 2; ++i)
        areg[i] = *(const u16x8*)&A[(size_t)(n0 + str + i * 32) * K + sc];
#pragma unroll
    for (int i = 0; i < 4; ++i)
        breg[i] = *(const u16x8*)&B[(size_t)(j0 + str + i * 32) * K + sc];

    for (int k0 = 0; k0 < K; k0 += 64) {
        __syncthreads();
#pragma unroll
        for (int i = 0; i < 2; ++i) *(u16x8*)&As[str + i * 32][sc] = areg[i];
#pragma unroll
        for (int i = 0; i < 4; ++i) *(u16x8*)&Bs[str + i * 32][sc] = breg[i];
        __syncthreads();
        if (k0 + 64 < K) {
#pragma unroll
            for (int i = 0; i < 2; ++i)
                areg[i] = *(const u16x8*)&A[(size_t)(n0 + str + i * 32) * K + k0 + 64 + sc];
#pragma unroll
            for (int i = 0; i < 4; ++i)
                breg[i] = *(const u16x8*)&B[(size_t)(j0 + str + i * 32) * K + k0 + 64 + sc];
        }
        __builtin_amdgcn_s_setprio(1);
#pragma unroll
        for (int kc = 0; kc < 2; ++kc) {
            bf16x8 af[2], bfr[4];
#pragma unroll
            for (int mf = 0; mf < 2; ++mf)
                af[mf] = *(const bf16x8*)&As[wr * 32 + mf * 16 + li][kc * 32 + lg * 8];
#pragma unroll
            for (int nf = 0; nf < 4; ++nf)
                bfr[nf] = *(const bf16x8*)&Bs[wc * 64 + nf * 16 + li][kc * 32 + lg * 8];
#pragma unroll
            for (int mf = 0; mf < 2; ++mf)
#pragma unroll
                for (int nf = 0; nf < 4; ++nf)
                    acc[mf][nf] = __builtin_amdgcn_mfma_f32_16x16x32_bf16(af[mf], bfr[nf], acc[mf][nf], 0, 0, 0);
        }
        __builtin_amdgcn_s_setprio(0);
    }
    const float scl = (j0 < 512) ? scaleA : scaleB;
#pragma unroll
    for (int mf = 0; mf < 2; ++mf) {
#pragma unroll
        for (int r = 0; r < 4; ++r) {
            const int row = n0 + wr * 32 + mf * 16 + lg * 4 + r;
#pragma unroll
            for (int nf = 0; nf < 4; ++nf) {
                const int col = j0 + wc * 64 + nf * 16 + li;
                float v = acc[mf][nf][r] * scl;
                if (ADD) v += addv[(size_t)row * N + col];
                if (BF16OUT) ((unsigned short*)Cv)[(size_t)row * N + col] = f2bf(v);
                else         ((float*)Cv)[(size_t)row * N + col] = v;
            }
        }
    }
}

// ---------------------------------------------------------------- MFMA flash attention, K-split x4
// ROUND-14 PROVEN STRUCTURE (unchanged): BQ=128, 8 waves x 16 q-rows; swapped QK^T;
// defer-max (THR=8); XOR-swizzled K/V LDS; launch_bounds(512,2).
__global__ __launch_bounds__(512, 2) void attn_mfma(const unsigned short* __restrict__ Qb,
                                                    const unsigned short* __restrict__ Kb,
                                                    const unsigned short* __restrict__ Vtb,
                                                    const int* __restrict__ prows,
                                                    const int* __restrict__ pcols,
                                                    const float* __restrict__ dist_bias,
                                                    unsigned short* __restrict__ Opart,
                                                    float* __restrict__ Mp,
                                                    float* __restrict__ Lp) {
    const int h  = blockIdx.y;
    const int n0 = blockIdx.x * BQ;
    const int sp = blockIdx.z;
    __shared__ unsigned short Ks[BK * HDIM];        // [64][128] XOR-swizzled
    __shared__ unsigned short Vts[HDIM * BK];       // [128][64] XOR-swizzled
    __shared__ unsigned short Ps[BQ][68];           // +4 pad
    __shared__ unsigned short biasTb[3043];
    __shared__ int krs[BK], kcs[BK];

    const int t    = threadIdx.x;
    const int lane = t & 63;
    const int lg   = lane >> 4;
    const int li   = lane & 15;
    const int qbase = (t >> 6) * 16;   // 8 waves x 16 q-rows

    for (int idx = t; idx < 3043; idx += 512) {
        float d  = sqrtf((float)idx);
        int bin  = (int)(log1pf(d) * (31.0f / 4.0529789877f));
        bin = bin > 31 ? 31 : bin;
        biasTb[idx] = f2bf(dist_bias[h * NBINS + bin]);
    }

    bf16x8 qf[4];
    {
        const unsigned short* qptr = &Qb[(size_t)(n0 + qbase + li) * QKSTR + h * HDIM];
#pragma unroll
        for (int kc = 0; kc < 4; ++kc)
            qf[kc] = *(const bf16x8*)&qptr[kc * 32 + lg * 8];
    }
    const int qrL = prows[n0 + qbase + li];
    const int qcL = pcols[n0 + qbase + li];

    float m_ = -1e30f;
    float l_ = 0.f;
    f32x4 accO[8];
#pragma unroll
    for (int dt = 0; dt < 8; ++dt) accO[dt] = (f32x4){0.f, 0.f, 0.f, 0.f};

    // staging (512 threads): K rows ktr,ktr+32; V rows vtr,vtr+64
    u16x8 kreg[2], vreg[2];
    int krreg = 0, kcreg = 0;
    const int ktr = t >> 4, kch = (t & 15) * 8;   // ktr 0..31
    const int vtr = t >> 3, vch = (t & 7) * 8;    // vtr 0..63

    const int kwofs0 = (ktr * 128 + kch) * 2;
    const int vwofs0 = (vtr * 64 + vch) * 2;

    int m0 = sp * KV_PER_SPLIT;
    {
#pragma unroll
        for (int i = 0; i < 2; ++i)
            kreg[i] = *(const u16x8*)&Kb[(size_t)(m0 + ktr + i * 32) * QKSTR + h * HDIM + kch];
#pragma unroll
        for (int i = 0; i < 2; ++i)
            vreg[i] = *(const u16x8*)&Vtb[(size_t)(h * HDIM + vtr + i * 64) * N_TOK + m0 + vch];
        if (t < BK) { krreg = prows[m0 + t]; kcreg = pcols[m0 + t]; }
    }

    for (int kb = 0; kb < KV_PER_SPLIT / BK; ++kb, m0 += BK) {
        __syncthreads();
#pragma unroll
        for (int i = 0; i < 2; ++i) {
            int ofs = (kwofs0 + i * 32 * 256) ^ ((ktr & 7) << 4);
            *(u16x8*)((char*)Ks + ofs) = kreg[i];
        }
#pragma unroll
        for (int i = 0; i < 2; ++i) {
            int ofs = (vwofs0 + i * 64 * 128) ^ ((vtr & 7) << 4);
            *(u16x8*)((char*)Vts + ofs) = vreg[i];
        }
        if (t < BK) { krs[t] = krreg; kcs[t] = kcreg; }
        __syncthreads();

        if (kb + 1 < KV_PER_SPLIT / BK) {
            const int m1 = m0 + BK;
#pragma unroll
            for (int i = 0; i < 2; ++i)
                kreg[i] = *(const u16x8*)&Kb[(size_t)(m1 + ktr + i * 32) * QKSTR + h * HDIM + kch];
#pragma unroll
            for (int i = 0; i < 2; ++i)
                vreg[i] = *(const u16x8*)&Vtb[(size_t)(h * HDIM + vtr + i * 64) * N_TOK + m1 + vch];
            if (t < BK) { krreg = prows[m1 + t]; kcreg = pcols[m1 + t]; }
        }

        // ---- S^T = K Q^T : lane gets P[q=li][k = jt*16 + lg*4 + r]
        f32x4 s[4];
        __builtin_amdgcn_s_setprio(1);
#pragma unroll
        for (int jt = 0; jt < 4; ++jt) {
            f32x4 acc = {0.f, 0.f, 0.f, 0.f};
#pragma unroll
            for (int kc = 0; kc < 4; ++kc) {
                int ofs = (((jt * 16 + li) * 128 + kc * 32 + lg * 8) * 2) ^ ((li & 7) << 4);
                bf16x8 kf = *(const bf16x8*)((const char*)Ks + ofs);
                acc = __builtin_amdgcn_mfma_f32_16x16x32_bf16(kf, qf[kc], acc, 0, 0, 0);
            }
            s[jt] = acc;
        }
        __builtin_amdgcn_s_setprio(0);

        // ---- bias
        float p[4][4];
#pragma unroll
        for (int jt = 0; jt < 4; ++jt) {
#pragma unroll
            for (int r = 0; r < 4; ++r) {
                int k  = jt * 16 + lg * 4 + r;
                int dr = qrL - krs[k], dc = qcL - kcs[k];
                p[jt][r] = s[jt][r] + bf2f(biasTb[dr * dr + dc * dc]);
            }
        }

        // ---- row max: tree + 2 shfl
        float t0 = fmaxf(fmaxf(p[0][0], p[0][1]), fmaxf(p[0][2], p[0][3]));
        float t1 = fmaxf(fmaxf(p[1][0], p[1][1]), fmaxf(p[1][2], p[1][3]));
        float t2 = fmaxf(fmaxf(p[2][0], p[2][1]), fmaxf(p[2][2], p[2][3]));
        float t3 = fmaxf(fmaxf(p[3][0], p[3][1]), fmaxf(p[3][2], p[3][3]));
        float pmax = fmaxf(fmaxf(t0, t1), fmaxf(t2, t3));
        pmax = fmaxf(pmax, __shfl_xor(pmax, 16));
        pmax = fmaxf(pmax, __shfl_xor(pmax, 32));

        // ---- defer-max (THR=8)
        if (!__all(pmax <= m_ + 8.0f)) {
            float mnew  = fmaxf(m_, pmax);
            float alpha = __expf(m_ - mnew);
            m_ = mnew;
            l_ *= alpha;
            float aq[4];
#pragma unroll
            for (int r = 0; r < 4; ++r)
                aq[r] = __shfl(alpha, (lane & 48) | (lg * 4 + r));
#pragma unroll
            for (int dt = 0; dt < 8; ++dt)
#pragma unroll
                for (int r = 0; r < 4; ++r) accO[dt][r] *= aq[r];
        }

        // ---- exp + row sum
        float rs = 0.f;
#pragma unroll
        for (int jt = 0; jt < 4; ++jt)
#pragma unroll
            for (int r = 0; r < 4; ++r) { p[jt][r] = __expf(p[jt][r] - m_); rs += p[jt][r]; }
        rs += __shfl_xor(rs, 16);
        rs += __shfl_xor(rs, 32);
        l_ += rs;

        // ---- P -> LDS (native bf16 cvt)
#pragma unroll
        for (int jt = 0; jt < 4; ++jt) {
            u16x4 w;
#pragma unroll
            for (int r = 0; r < 4; ++r) w[r] = f2bf_hw(p[jt][r]);
            *(u16x4*)&Ps[qbase + li][jt * 16 + lg * 4] = w;
        }

        // ---- O += P V
        bf16x8 pf0 = *(const bf16x8*)&Ps[qbase + li][lg * 8];
        bf16x8 pf1 = *(const bf16x8*)&Ps[qbase + li][32 + lg * 8];
        __builtin_amdgcn_s_setprio(1);
#pragma unroll
        for (int dt = 0; dt < 8; ++dt) {
            int ofs0 = (((dt * 16 + li) * 64 + lg * 8) * 2) ^ ((li & 7) << 4);
            bf16x8 vf0 = *(const bf16x8*)((const char*)Vts + ofs0);
            bf16x8 vf1 = *(const bf16x8*)((const char*)Vts + (ofs0 ^ 64));
            accO[dt] = __builtin_amdgcn_mfma_f32_16x16x32_bf16(pf0, vf0, accO[dt], 0, 0, 0);
            accO[dt] = __builtin_amdgcn_mfma_f32_16x16x32_bf16(pf1, vf1, accO[dt], 0, 0, 0);
        }
        __builtin_amdgcn_s_setprio(0);
    }

    // ---- epilogue
    float linv[4];
#pragma unroll
    for (int r = 0; r < 4; ++r)
        linv[r] = __shfl(l_, (lane & 48) | (lg * 4 + r));
#pragma unroll
    for (int r = 0; r < 4; ++r) {
        float inv = 1.0f / linv[r];
        int row = n0 + qbase + lg * 4 + r;
#pragma unroll
        for (int dt = 0; dt < 8; ++dt)
            Opart[(size_t)sp * N_TOK * DMODEL + (size_t)row * DMODEL + h * HDIM + dt * 16 + li] =
                f2bf(accO[dt][r] * inv);
    }
    if (lane < 16) {
        int row = n0 + qbase + lane;
        Mp[((size_t)sp * NHEAD + h) * N_TOK + row] = m_;
        Lp[((size_t)sp * NHEAD + h) * N_TOK + row] = l_;
    }
}

// ---------------------------------------------------------------- combine 4 K-split partials -> bf16
__global__ __launch_bounds__(256) void combine_kernel(const unsigned short* __restrict__ Opart,
                                                      const float* __restrict__ Mp,
                                                      const float* __restrict__ Lp,
                                                      unsigned short* __restrict__ outbf) {
    int n = blockIdx.x, t = threadIdx.x;
#pragma unroll
    for (int d0 = t; d0 < DMODEL; d0 += 256) {
        int h = d0 >> 7;
        float mm[NSPLIT], ll[NSPLIT];
        float m = -1e30f;
#pragma unroll
        for (int s = 0; s < NSPLIT; ++s) {
            mm[s] = Mp[((size_t)s * NHEAD + h) * N_TOK + n];
            ll[s] = Lp[((size_t)s * NHEAD + h) * N_TOK + n];
            m = fmaxf(m, mm[s]);
        }
        float acc = 0.f, lsum = 0.f;
#pragma unroll
        for (int s = 0; s < NSPLIT; ++s) {
            float a = __expf(mm[s] - m) * ll[s];
            lsum += a;
            acc += a * bf2f(Opart[(size_t)s * N_TOK * DMODEL + (size_t)n * DMODEL + d0]);
        }
        outbf[(size_t)n * DMODEL + d0] = f2bf(acc / lsum);
    }
}

// ---------------------------------------------------------------- LN + gated residual
__global__ __launch_bounds__(256) void final_kernel(const float* __restrict__ o,
                                                    const float* __restrict__ vh,
                                                    const float* __restrict__ lnw,
                                                    const float* __restrict__ lnb,
                                                    const float* __restrict__ gparam,
                                                    float* __restrict__ out) {
    int n = blockIdx.x, t = threadIdx.x;
    size_t base = (size_t)n * DMODEL;
    float x0 = o[base + t], x1 = o[base + t + 256];
    __shared__ float red[4];
    float v = x0 + x1;
#pragma unroll
    for (int off = 32; off > 0; off >>= 1) v += __shfl_down(v, off, 64);
    if ((t & 63) == 0) red[t >> 6] = v;
    __syncthreads();
    float mu = (red[0] + red[1] + red[2] + red[3]) * (1.0f / 512.0f);
    __syncthreads();
    float d0 = x0 - mu, d1 = x1 - mu;
    v = d0 * d0 + d1 * d1;
#pragma unroll
    for (int off = 32; off > 0; off >>= 1) v += __shfl_down(v, off, 64);
    if ((t & 63) == 0) red[t >> 6] = v;
    __syncthreads();
    float var  = (red[0] + red[1] + red[2] + red[3]) * (1.0f / 512.0f);
    float rstd = rsqrtf(var + 1e-5f);
    float gamma = log1pf(expf(gparam[0]));
    out[base + t]       = vh[base + t]       + gamma * (d0 * rstd * lnw[t]       + lnb[t]);
    out[base + t + 256] = vh[base + t + 256] + gamma * (d1 * rstd * lnw[t + 256] + lnb[t + 256]);
}

// ---------------------------------------------------------------- launch
extern "C" void kernel_launch(void* const* d_in, const int* in_sizes, int n_in,
                              void* d_out, int out_size, void* d_ws, size_t ws_size,
                              hipStream_t stream) {
    const float* vision_h  = (const float*)d_in[0];
    const int*   prows     = (const int*)d_in[1];
    const int*   pcols     = (const int*)d_in[2];
    const float* pos_w     = (const float*)d_in[3];
    const float* q_w       = (const float*)d_in[4];
    const float* k_w       = (const float*)d_in[5];
    const float* v_w       = (const float*)d_in[6];
    const float* out_w     = (const float*)d_in[7];
    const float* dist_bias = (const float*)d_in[8];
    const float* gamma_p   = (const float*)d_in[9];
    const float* ln_w      = (const float*)d_in[10];
    const float* ln_b      = (const float*)d_in[11];
    float* out = (float*)d_out;
    char* base = (char*)d_ws;

    const size_t MB = 1024 * 1024;
    unsigned short* vh_bf   = (unsigned short*)(base + 4  * MB);
    unsigned short* hpos_bf = (unsigned short*)(base + 8  * MB);
    unsigned short* Opart   = (unsigned short*)(base + 0);        // 16MB, after vh/hpos dead
    float*          ob      = (float*)(base + 0);                 // 8MB, after Opart dead
    unsigned short* QKb     = (unsigned short*)(base + 16 * MB);  // 8MB fused Q|K [4096][1024]
    unsigned short* Vtb     = (unsigned short*)(base + 24 * MB);  // 4MB
    unsigned short* attn_bf = (unsigned short*)(base + 28 * MB);  // 4MB
    float*          Mp      = (float*)(base + 32 * MB);           // 256KB
    float*          Lp      = (float*)(base + 32 * MB + 262144);  // 256KB
    unsigned short* wbf     = (unsigned short*)(base + 32 * MB + 524288);  // 2.5MB -> ends ~35MB
    float*          contrib = (float*)(base + 35 * MB);           // 80x512 f32 = 160KB

    unsigned short* w_q   = wbf + 1 * DMODEL * DMODEL;  // w_q||w_k contiguous -> fused B [1024][512]
    unsigned short* w_v   = wbf + 3 * DMODEL * DMODEL;
    unsigned short* w_o   = wbf + 4 * DMODEL * DMODEL;

    const float qscale = 0.08838834764831845f;  // 1/sqrt(128)

    prep2_kernel<<<1600, 256, 0, stream>>>(pos_w, q_w, k_w, v_w, out_w, pos_w, wbf, contrib);
    hpos_kernel<<<N_TOK, 256, 0, stream>>>(prows, pcols, vision_h, contrib, vh_bf, hpos_bf);
    // fused [Q|K] = h_pos @ [w_q;w_k]^T  (cols<512 scaled by qscale)
    gemm_mfma<false, true ><<<dim3(64, 8), 256, 0, stream>>>(hpos_bf, w_q, nullptr, QKb,
                                                             N_TOK, 1024, DMODEL, qscale, 1.0f);
    // Vt = v_w @ vision_h^T
    gemm_mfma<false, true ><<<dim3(8, 32), 256, 0, stream>>>(w_v, vh_bf, nullptr, Vtb,
                                                             DMODEL, N_TOK, DMODEL, 1.0f, 1.0f);
    attn_mfma<<<dim3(N_TOK / BQ, NHEAD, NSPLIT), 512, 0, stream>>>(QKb, QKb + 512, Vtb, prows, pcols,
                                                                   dist_bias, Opart, Mp, Lp);
    combine_kernel<<<N_TOK, 256, 0, stream>>>(Opart, Mp, Lp, attn_bf);
    gemm_mfma<false, false><<<dim3(64, 4), 256, 0, stream>>>(attn_bf, w_o, nullptr, ob,
                                                             N_TOK, DMODEL, DMODEL, 1.0f, 1.0f);
    final_kernel<<<N_TOK, 256, 0, stream>>>(ob, vision_h, ln_w, ln_b, gamma_p, out);
}

// Round 18
// 139.604 us; speedup vs baseline: 1.1157x; 1.0251x over previous
//
#include <hip/hip_runtime.h>
#include <math.h>

#define N_TOK 4096
#define DMODEL 512
#define NHEAD 4
#define HDIM 128
#define NBINS 32
#define BQ 128
#define BK 64
#define NSPLIT 4
#define KV_PER_SPLIT (N_TOK / NSPLIT)
#define QKSTR 1024   // row stride of fused Q|K buffer
#define MAXG 40

typedef __attribute__((ext_vector_type(8))) short bf16x8;
typedef __attribute__((ext_vector_type(4))) float f32x4;
typedef __attribute__((ext_vector_type(8))) unsigned short u16x8;
typedef __attribute__((ext_vector_type(4))) unsigned short u16x4;

__device__ __forceinline__ unsigned short f2bf(float x) {
    unsigned int u = __float_as_uint(x);
    u += 0x7FFFu + ((u >> 16) & 1u);   // round-to-nearest-even
    return (unsigned short)(u >> 16);
}
// native bf16 convert (compiler emits v_cvt_pk_bf16_f32, gfx950-native)
__device__ __forceinline__ unsigned short f2bf_hw(float x) {
    __bf16 b = (__bf16)x;
    union { __bf16 h; unsigned short u; } c;
    c.h = b;
    return c.u;
}
__device__ __forceinline__ float bf2f(unsigned short u) {
    return __uint_as_float(((unsigned int)u) << 16);
}

// ---------------------------------------------------------------- fused prep:
// blocks [0,1280): 5 weights fp32->bf16 ; blocks [1280,1600): PE contribution tables.
__global__ __launch_bounds__(256) void prep2_kernel(const float* __restrict__ w0, const float* __restrict__ w1,
                                                    const float* __restrict__ w2, const float* __restrict__ w3,
                                                    const float* __restrict__ w4,
                                                    const float* __restrict__ pos_w,
                                                    unsigned short* __restrict__ wbf,
                                                    float* __restrict__ contrib) {
    const int bid = blockIdx.x, t = threadIdx.x;
    if (bid < 1280) {
        const float* srcs[5] = {w0, w1, w2, w3, w4};
        const float* src = srcs[bid >> 8];
        unsigned short* dst = wbf + (size_t)(bid >> 8) * DMODEL * DMODEL;
        int idx = ((bid & 255) * 256 + t) * 4;
        float4 v = *(const float4*)&src[idx];
        u16x4 r;
        r[0] = f2bf(v.x); r[1] = f2bf(v.y); r[2] = f2bf(v.z); r[3] = f2bf(v.w);
        *(u16x4*)&dst[idx] = r;
    } else {
        const int q  = bid - 1280;       // 0..319
        const int p  = q >> 2;           // 0..79
        const int cy = q & 3;            // 128-col slice
        const bool isRow = p < MAXG;
        const float pos = (float)(isRow ? p : p - MAXG);
        __shared__ float pe[256];
        {
            int k = t >> 1;
            float freq = expf(-0.035977892078032f * (float)(2 * k));
            float ang = pos * freq;
            pe[t] = (t & 1) ? cosf(ang) : sinf(ang);
        }
        __syncthreads();
        const int jofs = isRow ? 0 : 256;
        const int col  = cy * 128 + (t >> 1);
        const int half = t & 1;
        const float* wrow = &pos_w[(size_t)col * DMODEL + jofs + half * 128];
        const float* peh  = &pe[half * 128];
        float acc = 0.f;
        for (int j = 0; j < 128; j += 4) {
            float4 w4 = *(const float4*)&wrow[j];
            acc += peh[j] * w4.x + peh[j + 1] * w4.y + peh[j + 2] * w4.z + peh[j + 3] * w4.w;
        }
        acc += __shfl_xor(acc, 1);
        if (half == 0) contrib[(size_t)p * DMODEL + col] = acc;
    }
}

// ---------------------------------------------------------------- h_pos = vh + contribR[row] + contribC[col]; also vh -> bf16
__global__ __launch_bounds__(256) void hpos_kernel(const int* __restrict__ rows,
                                                   const int* __restrict__ cols,
                                                   const float* __restrict__ vh,
                                                   const float* __restrict__ contrib,
                                                   unsigned short* __restrict__ vh_bf,
                                                   unsigned short* __restrict__ hpos_bf) {
    const int n = blockIdx.x, t = threadIdx.x;
    const float* rc = &contrib[(size_t)rows[n] * DMODEL];
    const float* cc = &contrib[(size_t)(MAXG + cols[n]) * DMODEL];
    const size_t base = (size_t)n * DMODEL;
    const int c = t * 2;
    float2 v = *(const float2*)&vh[base + c];
    vh_bf[base + c]     = f2bf(v.x);
    vh_bf[base + c + 1] = f2bf(v.y);
    float2 r = *(const float2*)&rc[c];
    float2 cl = *(const float2*)&cc[c];
    hpos_bf[base + c]     = f2bf(v.x + r.x + cl.x);
    hpos_bf[base + c + 1] = f2bf(v.y + r.y + cl.y);
}

// ---------------------------------------------------------------- MFMA GEMM: C[M][N] = A[M][K] @ B[N][K]^T
// ROUND-14 PROVEN: 64x128 tile, reg-prefetch staging, 4 waves 2x2 (wave tile 32x64).
template <bool ADD, bool BF16OUT>
__global__ __launch_bounds__(256) void gemm_mfma(const unsigned short* __restrict__ A,
                                                 const unsigned short* __restrict__ B,
                                                 const float* __restrict__ addv,
                                                 void* __restrict__ Cv,
                                                 int M, int N, int K,
                                                 float scaleA, float scaleB) {
    const int n0 = blockIdx.x * 64;
    const int j0 = blockIdx.y * 128;
    __shared__ unsigned short As[64][72];
    __shared__ unsigned short Bs[128][72];
    const int t    = threadIdx.x;
    const int wid  = t >> 6;
    const int wr   = wid >> 1, wc = wid & 1;
    const int lane = t & 63;
    const int lg   = lane >> 4, li = lane & 15;
    const int str  = t >> 3;          // 0..31
    const int sc   = (t & 7) * 8;

    f32x4 acc[2][4];
#pragma unroll
    for (int i = 0; i < 2; ++i)
#pragma unroll
        for (int j = 0; j < 4; ++j) acc[i][j] = (f32x4){0.f, 0.f, 0.f, 0.f};

    u16x8 areg[2], breg[4];
#pragma unroll
    for (int i = 0; i < 2; ++i)
        areg[i] = *(const u16x8*)&A[(size_t)(n0 + str + i * 32) * K + sc];
#pragma unroll
    for (int i = 0; i < 4; ++i)
        breg[i] = *(const u16x8*)&B[(size_t)(j0 + str + i * 32) * K + sc];

    for (int k0 = 0; k0 < K; k0 += 64) {
        __syncthreads();
#pragma unroll
        for (int i = 0; i < 2; ++i) *(u16x8*)&As[str + i * 32][sc] = areg[i];
#pragma unroll
        for (int i = 0; i < 4; ++i) *(u16x8*)&Bs[str + i * 32][sc] = breg[i];
        __syncthreads();
        if (k0 + 64 < K) {
#pragma unroll
            for (int i = 0; i < 2; ++i)
                areg[i] = *(const u16x8*)&A[(size_t)(n0 + str + i * 32) * K + k0 + 64 + sc];
#pragma unroll
            for (int i = 0; i < 4; ++i)
                breg[i] = *(const u16x8*)&B[(size_t)(j0 + str + i * 32) * K + k0 + 64 + sc];
        }
        __builtin_amdgcn_s_setprio(1);
#pragma unroll
        for (int kc = 0; kc < 2; ++kc) {
            bf16x8 af[2], bfr[4];
#pragma unroll
            for (int mf = 0; mf < 2; ++mf)
                af[mf] = *(const bf16x8*)&As[wr * 32 + mf * 16 + li][kc * 32 + lg * 8];
#pragma unroll
            for (int nf = 0; nf < 4; ++nf)
                bfr[nf] = *(const bf16x8*)&Bs[wc * 64 + nf * 16 + li][kc * 32 + lg * 8];
#pragma unroll
            for (int mf = 0; mf < 2; ++mf)
#pragma unroll
                for (int nf = 0; nf < 4; ++nf)
                    acc[mf][nf] = __builtin_amdgcn_mfma_f32_16x16x32_bf16(af[mf], bfr[nf], acc[mf][nf], 0, 0, 0);
        }
        __builtin_amdgcn_s_setprio(0);
    }
    const float scl = (j0 < 512) ? scaleA : scaleB;
#pragma unroll
    for (int mf = 0; mf < 2; ++mf) {
#pragma unroll
        for (int r = 0; r < 4; ++r) {
            const int row = n0 + wr * 32 + mf * 16 + lg * 4 + r;
#pragma unroll
            for (int nf = 0; nf < 4; ++nf) {
                const int col = j0 + wc * 64 + nf * 16 + li;
                float v = acc[mf][nf][r] * scl;
                if (ADD) v += addv[(size_t)row * N + col];
                if (BF16OUT) ((unsigned short*)Cv)[(size_t)row * N + col] = f2bf(v);
                else         ((float*)Cv)[(size_t)row * N + col] = v;
            }
        }
    }
}

// ---------------------------------------------------------------- MFMA flash attention, K-split x4
// ROUND-14 PROVEN STRUCTURE (unchanged): BQ=128, 8 waves x 16 q-rows; swapped QK^T;
// defer-max (THR=8); XOR-swizzled K/V LDS; launch_bounds(512,2).
__global__ __launch_bounds__(512, 2) void attn_mfma(const unsigned short* __restrict__ Qb,
                                                    const unsigned short* __restrict__ Kb,
                                                    const unsigned short* __restrict__ Vtb,
                                                    const int* __restrict__ prows,
                                                    const int* __restrict__ pcols,
                                                    const float* __restrict__ dist_bias,
                                                    unsigned short* __restrict__ Opart,
                                                    float* __restrict__ Mp,
                                                    float* __restrict__ Lp) {
    const int h  = blockIdx.y;
    const int n0 = blockIdx.x * BQ;
    const int sp = blockIdx.z;
    __shared__ unsigned short Ks[BK * HDIM];        // [64][128] XOR-swizzled
    __shared__ unsigned short Vts[HDIM * BK];       // [128][64] XOR-swizzled
    __shared__ unsigned short Ps[BQ][68];           // +4 pad
    __shared__ unsigned short biasTb[3043];
    __shared__ int krs[BK], kcs[BK];

    const int t    = threadIdx.x;
    const int lane = t & 63;
    const int lg   = lane >> 4;
    const int li   = lane & 15;
    const int qbase = (t >> 6) * 16;   // 8 waves x 16 q-rows

    for (int idx = t; idx < 3043; idx += 512) {
        float d  = sqrtf((float)idx);
        int bin  = (int)(log1pf(d) * (31.0f / 4.0529789877f));
        bin = bin > 31 ? 31 : bin;
        biasTb[idx] = f2bf(dist_bias[h * NBINS + bin]);
    }

    bf16x8 qf[4];
    {
        const unsigned short* qptr = &Qb[(size_t)(n0 + qbase + li) * QKSTR + h * HDIM];
#pragma unroll
        for (int kc = 0; kc < 4; ++kc)
            qf[kc] = *(const bf16x8*)&qptr[kc * 32 + lg * 8];
    }
    const int qrL = prows[n0 + qbase + li];
    const int qcL = pcols[n0 + qbase + li];

    float m_ = -1e30f;
    float l_ = 0.f;
    f32x4 accO[8];
#pragma unroll
    for (int dt = 0; dt < 8; ++dt) accO[dt] = (f32x4){0.f, 0.f, 0.f, 0.f};

    u16x8 kreg[2], vreg[2];
    int krreg = 0, kcreg = 0;
    const int ktr = t >> 4, kch = (t & 15) * 8;
    const int vtr = t >> 3, vch = (t & 7) * 8;

    const int kwofs0 = (ktr * 128 + kch) * 2;
    const int vwofs0 = (vtr * 64 + vch) * 2;

    int m0 = sp * KV_PER_SPLIT;
    {
#pragma unroll
        for (int i = 0; i < 2; ++i)
            kreg[i] = *(const u16x8*)&Kb[(size_t)(m0 + ktr + i * 32) * QKSTR + h * HDIM + kch];
#pragma unroll
        for (int i = 0; i < 2; ++i)
            vreg[i] = *(const u16x8*)&Vtb[(size_t)(h * HDIM + vtr + i * 64) * N_TOK + m0 + vch];
        if (t < BK) { krreg = prows[m0 + t]; kcreg = pcols[m0 + t]; }
    }

    for (int kb = 0; kb < KV_PER_SPLIT / BK; ++kb, m0 += BK) {
        __syncthreads();
#pragma unroll
        for (int i = 0; i < 2; ++i) {
            int ofs = (kwofs0 + i * 32 * 256) ^ ((ktr & 7) << 4);
            *(u16x8*)((char*)Ks + ofs) = kreg[i];
        }
#pragma unroll
        for (int i = 0; i < 2; ++i) {
            int ofs = (vwofs0 + i * 64 * 128) ^ ((vtr & 7) << 4);
            *(u16x8*)((char*)Vts + ofs) = vreg[i];
        }
        if (t < BK) { krs[t] = krreg; kcs[t] = kcreg; }
        __syncthreads();

        if (kb + 1 < KV_PER_SPLIT / BK) {
            const int m1 = m0 + BK;
#pragma unroll
            for (int i = 0; i < 2; ++i)
                kreg[i] = *(const u16x8*)&Kb[(size_t)(m1 + ktr + i * 32) * QKSTR + h * HDIM + kch];
#pragma unroll
            for (int i = 0; i < 2; ++i)
                vreg[i] = *(const u16x8*)&Vtb[(size_t)(h * HDIM + vtr + i * 64) * N_TOK + m1 + vch];
            if (t < BK) { krreg = prows[m1 + t]; kcreg = pcols[m1 + t]; }
        }

        // ---- S^T = K Q^T
        f32x4 s[4];
        __builtin_amdgcn_s_setprio(1);
#pragma unroll
        for (int jt = 0; jt < 4; ++jt) {
            f32x4 acc = {0.f, 0.f, 0.f, 0.f};
#pragma unroll
            for (int kc = 0; kc < 4; ++kc) {
                int ofs = (((jt * 16 + li) * 128 + kc * 32 + lg * 8) * 2) ^ ((li & 7) << 4);
                bf16x8 kf = *(const bf16x8*)((const char*)Ks + ofs);
                acc = __builtin_amdgcn_mfma_f32_16x16x32_bf16(kf, qf[kc], acc, 0, 0, 0);
            }
            s[jt] = acc;
        }
        __builtin_amdgcn_s_setprio(0);

        // ---- bias
        float p[4][4];
#pragma unroll
        for (int jt = 0; jt < 4; ++jt) {
#pragma unroll
            for (int r = 0; r < 4; ++r) {
                int k  = jt * 16 + lg * 4 + r;
                int dr = qrL - krs[k], dc = qcL - kcs[k];
                p[jt][r] = s[jt][r] + bf2f(biasTb[dr * dr + dc * dc]);
            }
        }

        // ---- row max: tree + 2 shfl
        float t0 = fmaxf(fmaxf(p[0][0], p[0][1]), fmaxf(p[0][2], p[0][3]));
        float t1 = fmaxf(fmaxf(p[1][0], p[1][1]), fmaxf(p[1][2], p[1][3]));
        float t2 = fmaxf(fmaxf(p[2][0], p[2][1]), fmaxf(p[2][2], p[2][3]));
        float t3 = fmaxf(fmaxf(p[3][0], p[3][1]), fmaxf(p[3][2], p[3][3]));
        float pmax = fmaxf(fmaxf(t0, t1), fmaxf(t2, t3));
        pmax = fmaxf(pmax, __shfl_xor(pmax, 16));
        pmax = fmaxf(pmax, __shfl_xor(pmax, 32));

        // ---- defer-max (THR=8)
        if (!__all(pmax <= m_ + 8.0f)) {
            float mnew  = fmaxf(m_, pmax);
            float alpha = __expf(m_ - mnew);
            m_ = mnew;
            l_ *= alpha;
            float aq[4];
#pragma unroll
            for (int r = 0; r < 4; ++r)
                aq[r] = __shfl(alpha, (lane & 48) | (lg * 4 + r));
#pragma unroll
            for (int dt = 0; dt < 8; ++dt)
#pragma unroll
                for (int r = 0; r < 4; ++r) accO[dt][r] *= aq[r];
        }

        // ---- exp + row sum
        float rs = 0.f;
#pragma unroll
        for (int jt = 0; jt < 4; ++jt)
#pragma unroll
            for (int r = 0; r < 4; ++r) { p[jt][r] = __expf(p[jt][r] - m_); rs += p[jt][r]; }
        rs += __shfl_xor(rs, 16);
        rs += __shfl_xor(rs, 32);
        l_ += rs;

        // ---- P -> LDS (native bf16 cvt)
#pragma unroll
        for (int jt = 0; jt < 4; ++jt) {
            u16x4 w;
#pragma unroll
            for (int r = 0; r < 4; ++r) w[r] = f2bf_hw(p[jt][r]);
            *(u16x4*)&Ps[qbase + li][jt * 16 + lg * 4] = w;
        }

        // ---- O += P V
        bf16x8 pf0 = *(const bf16x8*)&Ps[qbase + li][lg * 8];
        bf16x8 pf1 = *(const bf16x8*)&Ps[qbase + li][32 + lg * 8];
        __builtin_amdgcn_s_setprio(1);
#pragma unroll
        for (int dt = 0; dt < 8; ++dt) {
            int ofs0 = (((dt * 16 + li) * 64 + lg * 8) * 2) ^ ((li & 7) << 4);
            bf16x8 vf0 = *(const bf16x8*)((const char*)Vts + ofs0);
            bf16x8 vf1 = *(const bf16x8*)((const char*)Vts + (ofs0 ^ 64));
            accO[dt] = __builtin_amdgcn_mfma_f32_16x16x32_bf16(pf0, vf0, accO[dt], 0, 0, 0);
            accO[dt] = __builtin_amdgcn_mfma_f32_16x16x32_bf16(pf1, vf1, accO[dt], 0, 0, 0);
        }
        __builtin_amdgcn_s_setprio(0);
    }

    // ---- epilogue
    float linv[4];
#pragma unroll
    for (int r = 0; r < 4; ++r)
        linv[r] = __shfl(l_, (lane & 48) | (lg * 4 + r));
#pragma unroll
    for (int r = 0; r < 4; ++r) {
        float inv = 1.0f / linv[r];
        int row = n0 + qbase + lg * 4 + r;
#pragma unroll
        for (int dt = 0; dt < 8; ++dt)
            Opart[(size_t)sp * N_TOK * DMODEL + (size_t)row * DMODEL + h * HDIM + dt * 16 + li] =
                f2bf(accO[dt][r] * inv);
    }
    if (lane < 16) {
        int row = n0 + qbase + lane;
        Mp[((size_t)sp * NHEAD + h) * N_TOK + row] = m_;
        Lp[((size_t)sp * NHEAD + h) * N_TOK + row] = l_;
    }
}

// ---------------------------------------------------------------- combine 4 K-split partials -> bf16
__global__ __launch_bounds__(256) void combine_kernel(const unsigned short* __restrict__ Opart,
                                                      const float* __restrict__ Mp,
                                                      const float* __restrict__ Lp,
                                                      unsigned short* __restrict__ outbf) {
    int n = blockIdx.x, t = threadIdx.x;
#pragma unroll
    for (int d0 = t; d0 < DMODEL; d0 += 256) {
        int h = d0 >> 7;
        float mm[NSPLIT], ll[NSPLIT];
        float m = -1e30f;
#pragma unroll
        for (int s = 0; s < NSPLIT; ++s) {
            mm[s] = Mp[((size_t)s * NHEAD + h) * N_TOK + n];
            ll[s] = Lp[((size_t)s * NHEAD + h) * N_TOK + n];
            m = fmaxf(m, mm[s]);
        }
        float acc = 0.f, lsum = 0.f;
#pragma unroll
        for (int s = 0; s < NSPLIT; ++s) {
            float a = __expf(mm[s] - m) * ll[s];
            lsum += a;
            acc += a * bf2f(Opart[(size_t)s * N_TOK * DMODEL + (size_t)n * DMODEL + d0]);
        }
        outbf[(size_t)n * DMODEL + d0] = f2bf(acc / lsum);
    }
}

// ---------------------------------------------------------------- LN + gated residual (bf16 o input)
__global__ __launch_bounds__(256) void final_kernel(const unsigned short* __restrict__ o,
                                                    const float* __restrict__ vh,
                                                    const float* __restrict__ lnw,
                                                    const float* __restrict__ lnb,
                                                    const float* __restrict__ gparam,
                                                    float* __restrict__ out) {
    int n = blockIdx.x, t = threadIdx.x;
    size_t base = (size_t)n * DMODEL;
    float x0 = bf2f(o[base + t]), x1 = bf2f(o[base + t + 256]);
    __shared__ float red[4];
    float v = x0 + x1;
#pragma unroll
    for (int off = 32; off > 0; off >>= 1) v += __shfl_down(v, off, 64);
    if ((t & 63) == 0) red[t >> 6] = v;
    __syncthreads();
    float mu = (red[0] + red[1] + red[2] + red[3]) * (1.0f / 512.0f);
    __syncthreads();
    float d0 = x0 - mu, d1 = x1 - mu;
    v = d0 * d0 + d1 * d1;
#pragma unroll
    for (int off = 32; off > 0; off >>= 1) v += __shfl_down(v, off, 64);
    if ((t & 63) == 0) red[t >> 6] = v;
    __syncthreads();
    float var  = (red[0] + red[1] + red[2] + red[3]) * (1.0f / 512.0f);
    float rstd = rsqrtf(var + 1e-5f);
    float gamma = log1pf(expf(gparam[0]));
    out[base + t]       = vh[base + t]       + gamma * (d0 * rstd * lnw[t]       + lnb[t]);
    out[base + t + 256] = vh[base + t + 256] + gamma * (d1 * rstd * lnw[t + 256] + lnb[t + 256]);
}

// ---------------------------------------------------------------- launch
extern "C" void kernel_launch(void* const* d_in, const int* in_sizes, int n_in,
                              void* d_out, int out_size, void* d_ws, size_t ws_size,
                              hipStream_t stream) {
    const float* vision_h  = (const float*)d_in[0];
    const int*   prows     = (const int*)d_in[1];
    const int*   pcols     = (const int*)d_in[2];
    const float* pos_w     = (const float*)d_in[3];
    const float* q_w       = (const float*)d_in[4];
    const float* k_w       = (const float*)d_in[5];
    const float* v_w       = (const float*)d_in[6];
    const float* out_w     = (const float*)d_in[7];
    const float* dist_bias = (const float*)d_in[8];
    const float* gamma_p   = (const float*)d_in[9];
    const float* ln_w      = (const float*)d_in[10];
    const float* ln_b      = (const float*)d_in[11];
    float* out = (float*)d_out;
    char* base = (char*)d_ws;

    const size_t MB = 1024 * 1024;
    unsigned short* vh_bf   = (unsigned short*)(base + 4  * MB);
    unsigned short* hpos_bf = (unsigned short*)(base + 8  * MB);
    unsigned short* Opart   = (unsigned short*)(base + 0);        // 16MB, after vh/hpos dead
    unsigned short* ob_bf   = (unsigned short*)(base + 0);        // 4MB, after Opart dead
    unsigned short* QKb     = (unsigned short*)(base + 16 * MB);  // 8MB fused Q|K [4096][1024]
    unsigned short* Vtb     = (unsigned short*)(base + 24 * MB);  // 4MB
    unsigned short* attn_bf = (unsigned short*)(base + 28 * MB);  // 4MB
    float*          Mp      = (float*)(base + 32 * MB);           // 256KB
    float*          Lp      = (float*)(base + 32 * MB + 262144);  // 256KB
    unsigned short* wbf     = (unsigned short*)(base + 32 * MB + 524288);  // 2.5MB
    float*          contrib = (float*)(base + 35 * MB);           // 80x512 f32 = 160KB

    unsigned short* w_q   = wbf + 1 * DMODEL * DMODEL;  // w_q||w_k contiguous -> fused B [1024][512]
    unsigned short* w_v   = wbf + 3 * DMODEL * DMODEL;
    unsigned short* w_o   = wbf + 4 * DMODEL * DMODEL;

    const float qscale = 0.08838834764831845f;  // 1/sqrt(128)

    prep2_kernel<<<1600, 256, 0, stream>>>(pos_w, q_w, k_w, v_w, out_w, pos_w, wbf, contrib);
    hpos_kernel<<<N_TOK, 256, 0, stream>>>(prows, pcols, vision_h, contrib, vh_bf, hpos_bf);
    // fused [Q|K] = h_pos @ [w_q;w_k]^T  (cols<512 scaled by qscale)
    gemm_mfma<false, true ><<<dim3(64, 8), 256, 0, stream>>>(hpos_bf, w_q, nullptr, QKb,
                                                             N_TOK, 1024, DMODEL, qscale, 1.0f);
    // Vt = v_w @ vision_h^T
    gemm_mfma<false, true ><<<dim3(8, 32), 256, 0, stream>>>(w_v, vh_bf, nullptr, Vtb,
                                                             DMODEL, N_TOK, DMODEL, 1.0f, 1.0f);
    attn_mfma<<<dim3(N_TOK / BQ, NHEAD, NSPLIT), 512, 0, stream>>>(QKb, QKb + 512, Vtb, prows, pcols,
                                                                   dist_bias, Opart, Mp, Lp);
    combine_kernel<<<N_TOK, 256, 0, stream>>>(Opart, Mp, Lp, attn_bf);
    // o = attn @ out_w^T (bf16 out: halves epilogue bytes; LN re-derives stats in f32)
    gemm_mfma<false, true ><<<dim3(64, 4), 256, 0, stream>>>(attn_bf, w_o, nullptr, ob_bf,
                                                             N_TOK, DMODEL, DMODEL, 1.0f, 1.0f);
    final_kernel<<<N_TOK, 256, 0, stream>>>(ob_bf, vision_h, ln_w, ln_b, gamma_p, out);
}

// Round 19
// 138.690 us; speedup vs baseline: 1.1230x; 1.0066x over previous
//
#include <hip/hip_runtime.h>
#include <math.h>

#define N_TOK 4096
#define DMODEL 512
#define NHEAD 4
#define HDIM 128
#define NBINS 32
#define BQ 128
#define BK 64
#define NSPLIT 4
#define KV_PER_SPLIT (N_TOK / NSPLIT)
#define QKSTR 1024   // row stride of fused Q|K buffer
#define MAXG 40

typedef __attribute__((ext_vector_type(8))) short bf16x8;
typedef __attribute__((ext_vector_type(4))) float f32x4;
typedef __attribute__((ext_vector_type(8))) unsigned short u16x8;
typedef __attribute__((ext_vector_type(4))) unsigned short u16x4;

__device__ __forceinline__ unsigned short f2bf(float x) {
    unsigned int u = __float_as_uint(x);
    u += 0x7FFFu + ((u >> 16) & 1u);   // round-to-nearest-even
    return (unsigned short)(u >> 16);
}
// native bf16 convert (compiler emits v_cvt_pk_bf16_f32, gfx950-native)
__device__ __forceinline__ unsigned short f2bf_hw(float x) {
    __bf16 b = (__bf16)x;
    union { __bf16 h; unsigned short u; } c;
    c.h = b;
    return c.u;
}
__device__ __forceinline__ float bf2f(unsigned short u) {
    return __uint_as_float(((unsigned int)u) << 16);
}

// ---------------------------------------------------------------- fused prep:
// blocks [0,1280): 5 weights fp32->bf16 ; blocks [1280,1600): PE contribution tables.
__global__ __launch_bounds__(256) void prep2_kernel(const float* __restrict__ w0, const float* __restrict__ w1,
                                                    const float* __restrict__ w2, const float* __restrict__ w3,
                                                    const float* __restrict__ w4,
                                                    const float* __restrict__ pos_w,
                                                    unsigned short* __restrict__ wbf,
                                                    float* __restrict__ contrib) {
    const int bid = blockIdx.x, t = threadIdx.x;
    if (bid < 1280) {
        const float* srcs[5] = {w0, w1, w2, w3, w4};
        const float* src = srcs[bid >> 8];
        unsigned short* dst = wbf + (size_t)(bid >> 8) * DMODEL * DMODEL;
        int idx = ((bid & 255) * 256 + t) * 4;
        float4 v = *(const float4*)&src[idx];
        u16x4 r;
        r[0] = f2bf(v.x); r[1] = f2bf(v.y); r[2] = f2bf(v.z); r[3] = f2bf(v.w);
        *(u16x4*)&dst[idx] = r;
    } else {
        const int q  = bid - 1280;       // 0..319
        const int p  = q >> 2;           // 0..79
        const int cy = q & 3;            // 128-col slice
        const bool isRow = p < MAXG;
        const float pos = (float)(isRow ? p : p - MAXG);
        __shared__ float pe[256];
        {
            int k = t >> 1;
            float freq = expf(-0.035977892078032f * (float)(2 * k));
            float ang = pos * freq;
            pe[t] = (t & 1) ? cosf(ang) : sinf(ang);
        }
        __syncthreads();
        const int jofs = isRow ? 0 : 256;
        const int col  = cy * 128 + (t >> 1);
        const int half = t & 1;
        const float* wrow = &pos_w[(size_t)col * DMODEL + jofs + half * 128];
        const float* peh  = &pe[half * 128];
        float acc = 0.f;
        for (int j = 0; j < 128; j += 4) {
            float4 w4 = *(const float4*)&wrow[j];
            acc += peh[j] * w4.x + peh[j + 1] * w4.y + peh[j + 2] * w4.z + peh[j + 3] * w4.w;
        }
        acc += __shfl_xor(acc, 1);
        if (half == 0) contrib[(size_t)p * DMODEL + col] = acc;
    }
}

// ---------------------------------------------------------------- h_pos = vh + contribR[row] + contribC[col]; also vh -> bf16
__global__ __launch_bounds__(256) void hpos_kernel(const int* __restrict__ rows,
                                                   const int* __restrict__ cols,
                                                   const float* __restrict__ vh,
                                                   const float* __restrict__ contrib,
                                                   unsigned short* __restrict__ vh_bf,
                                                   unsigned short* __restrict__ hpos_bf) {
    const int n = blockIdx.x, t = threadIdx.x;
    const float* rc = &contrib[(size_t)rows[n] * DMODEL];
    const float* cc = &contrib[(size_t)(MAXG + cols[n]) * DMODEL];
    const size_t base = (size_t)n * DMODEL;
    const int c = t * 2;
    float2 v = *(const float2*)&vh[base + c];
    vh_bf[base + c]     = f2bf(v.x);
    vh_bf[base + c + 1] = f2bf(v.y);
    float2 r = *(const float2*)&rc[c];
    float2 cl = *(const float2*)&cc[c];
    hpos_bf[base + c]     = f2bf(v.x + r.x + cl.x);
    hpos_bf[base + c + 1] = f2bf(v.y + r.y + cl.y);
}

// ---------------------------------------------------------------- MFMA GEMM: C[M][N] = A[M][K] @ B[N][K]^T
// ROUND-14 PROVEN: 64x128 tile, reg-prefetch staging, 4 waves 2x2 (wave tile 32x64).
template <bool ADD, bool BF16OUT>
__global__ __launch_bounds__(256) void gemm_mfma(const unsigned short* __restrict__ A,
                                                 const unsigned short* __restrict__ B,
                                                 const float* __restrict__ addv,
                                                 void* __restrict__ Cv,
                                                 int M, int N, int K,
                                                 float scaleA, float scaleB) {
    const int n0 = blockIdx.x * 64;
    const int j0 = blockIdx.y * 128;
    __shared__ unsigned short As[64][72];
    __shared__ unsigned short Bs[128][72];
    const int t    = threadIdx.x;
    const int wid  = t >> 6;
    const int wr   = wid >> 1, wc = wid & 1;
    const int lane = t & 63;
    const int lg   = lane >> 4, li = lane & 15;
    const int str  = t >> 3;          // 0..31
    const int sc   = (t & 7) * 8;

    f32x4 acc[2][4];
#pragma unroll
    for (int i = 0; i < 2; ++i)
#pragma unroll
        for (int j = 0; j < 4; ++j) acc[i][j] = (f32x4){0.f, 0.f, 0.f, 0.f};

    u16x8 areg[2], breg[4];
#pragma unroll
    for (int i = 0; i < 2; ++i)
        areg[i] = *(const u16x8*)&A[(size_t)(n0 + str + i * 32) * K + sc];
#pragma unroll
    for (int i = 0; i < 4; ++i)
        breg[i] = *(const u16x8*)&B[(size_t)(j0 + str + i * 32) * K + sc];

    for (int k0 = 0; k0 < K; k0 += 64) {
        __syncthreads();
#pragma unroll
        for (int i = 0; i < 2; ++i) *(u16x8*)&As[str + i * 32][sc] = areg[i];
#pragma unroll
        for (int i = 0; i < 4; ++i) *(u16x8*)&Bs[str + i * 32][sc] = breg[i];
        __syncthreads();
        if (k0 + 64 < K) {
#pragma unroll
            for (int i = 0; i < 2; ++i)
                areg[i] = *(const u16x8*)&A[(size_t)(n0 + str + i * 32) * K + k0 + 64 + sc];
#pragma unroll
            for (int i = 0; i < 4; ++i)
                breg[i] = *(const u16x8*)&B[(size_t)(j0 + str + i * 32) * K + k0 + 64 + sc];
        }
        __builtin_amdgcn_s_setprio(1);
#pragma unroll
        for (int kc = 0; kc < 2; ++kc) {
            bf16x8 af[2], bfr[4];
#pragma unroll
            for (int mf = 0; mf < 2; ++mf)
                af[mf] = *(const bf16x8*)&As[wr * 32 + mf * 16 + li][kc * 32 + lg * 8];
#pragma unroll
            for (int nf = 0; nf < 4; ++nf)
                bfr[nf] = *(const bf16x8*)&Bs[wc * 64 + nf * 16 + li][kc * 32 + lg * 8];
#pragma unroll
            for (int mf = 0; mf < 2; ++mf)
#pragma unroll
                for (int nf = 0; nf < 4; ++nf)
                    acc[mf][nf] = __builtin_amdgcn_mfma_f32_16x16x32_bf16(af[mf], bfr[nf], acc[mf][nf], 0, 0, 0);
        }
        __builtin_amdgcn_s_setprio(0);
    }
    const float scl = (j0 < 512) ? scaleA : scaleB;
#pragma unroll
    for (int mf = 0; mf < 2; ++mf) {
#pragma unroll
        for (int r = 0; r < 4; ++r) {
            const int row = n0 + wr * 32 + mf * 16 + lg * 4 + r;
#pragma unroll
            for (int nf = 0; nf < 4; ++nf) {
                const int col = j0 + wc * 64 + nf * 16 + li;
                float v = acc[mf][nf][r] * scl;
                if (ADD) v += addv[(size_t)row * N + col];
                if (BF16OUT) ((unsigned short*)Cv)[(size_t)row * N + col] = f2bf(v);
                else         ((float*)Cv)[(size_t)row * N + col] = v;
            }
        }
    }
}

// ---------------------------------------------------------------- combined-A fragment for out-proj GEMM
// A[row][kk..kk+8) = (sum_s exp(m_s - m)*l_s * Opart_s[row]) / lsum  (identical math to combine_kernel)
__device__ __forceinline__ u16x8 combineA(const unsigned short* __restrict__ Opart,
                                          const float* __restrict__ Mp,
                                          const float* __restrict__ Lp,
                                          int row, int kk) {
    const int h = kk >> 7;
    float ms[NSPLIT], ls[NSPLIT], mm = -1e30f;
#pragma unroll
    for (int s = 0; s < NSPLIT; ++s) {
        ms[s] = Mp[((size_t)s * NHEAD + h) * N_TOK + row];
        ls[s] = Lp[((size_t)s * NHEAD + h) * N_TOK + row];
        mm = fmaxf(mm, ms[s]);
    }
    float ws[NSPLIT], lsum = 0.f;
#pragma unroll
    for (int s = 0; s < NSPLIT; ++s) { ws[s] = __expf(ms[s] - mm) * ls[s]; lsum += ws[s]; }
    const float inv = 1.0f / lsum;
    float acc[8] = {0.f, 0.f, 0.f, 0.f, 0.f, 0.f, 0.f, 0.f};
#pragma unroll
    for (int s = 0; s < NSPLIT; ++s) {
        u16x8 o = *(const u16x8*)&Opart[(size_t)s * N_TOK * DMODEL + (size_t)row * DMODEL + kk];
#pragma unroll
        for (int e = 0; e < 8; ++e) acc[e] += ws[s] * bf2f(o[e]);
    }
    u16x8 r;
#pragma unroll
    for (int e = 0; e < 8; ++e) r[e] = f2bf_hw(acc[e] * inv);
    return r;
}

// ---------------------------------------------------------------- out-proj GEMM with fused split-combine
// C[4096][512] = combine(Opart) @ w_o^T, bf16 out. Same tile machinery as gemm_mfma.
__global__ __launch_bounds__(256) void gemm_out(const unsigned short* __restrict__ Opart,
                                                const float* __restrict__ Mp,
                                                const float* __restrict__ Lp,
                                                const unsigned short* __restrict__ B,
                                                unsigned short* __restrict__ C) {
    const int n0 = blockIdx.x * 64;
    const int j0 = blockIdx.y * 128;
    const int K = DMODEL, N = DMODEL;
    __shared__ unsigned short As[64][72];
    __shared__ unsigned short Bs[128][72];
    const int t    = threadIdx.x;
    const int wid  = t >> 6;
    const int wr   = wid >> 1, wc = wid & 1;
    const int lane = t & 63;
    const int lg   = lane >> 4, li = lane & 15;
    const int str  = t >> 3;
    const int sc   = (t & 7) * 8;

    f32x4 acc[2][4];
#pragma unroll
    for (int i = 0; i < 2; ++i)
#pragma unroll
        for (int j = 0; j < 4; ++j) acc[i][j] = (f32x4){0.f, 0.f, 0.f, 0.f};

    u16x8 areg[2], breg[4];
#pragma unroll
    for (int i = 0; i < 2; ++i)
        areg[i] = combineA(Opart, Mp, Lp, n0 + str + i * 32, sc);
#pragma unroll
    for (int i = 0; i < 4; ++i)
        breg[i] = *(const u16x8*)&B[(size_t)(j0 + str + i * 32) * K + sc];

    for (int k0 = 0; k0 < K; k0 += 64) {
        __syncthreads();
#pragma unroll
        for (int i = 0; i < 2; ++i) *(u16x8*)&As[str + i * 32][sc] = areg[i];
#pragma unroll
        for (int i = 0; i < 4; ++i) *(u16x8*)&Bs[str + i * 32][sc] = breg[i];
        __syncthreads();
        if (k0 + 64 < K) {
#pragma unroll
            for (int i = 0; i < 2; ++i)
                areg[i] = combineA(Opart, Mp, Lp, n0 + str + i * 32, k0 + 64 + sc);
#pragma unroll
            for (int i = 0; i < 4; ++i)
                breg[i] = *(const u16x8*)&B[(size_t)(j0 + str + i * 32) * K + k0 + 64 + sc];
        }
        __builtin_amdgcn_s_setprio(1);
#pragma unroll
        for (int kc = 0; kc < 2; ++kc) {
            bf16x8 af[2], bfr[4];
#pragma unroll
            for (int mf = 0; mf < 2; ++mf)
                af[mf] = *(const bf16x8*)&As[wr * 32 + mf * 16 + li][kc * 32 + lg * 8];
#pragma unroll
            for (int nf = 0; nf < 4; ++nf)
                bfr[nf] = *(const bf16x8*)&Bs[wc * 64 + nf * 16 + li][kc * 32 + lg * 8];
#pragma unroll
            for (int mf = 0; mf < 2; ++mf)
#pragma unroll
                for (int nf = 0; nf < 4; ++nf)
                    acc[mf][nf] = __builtin_amdgcn_mfma_f32_16x16x32_bf16(af[mf], bfr[nf], acc[mf][nf], 0, 0, 0);
        }
        __builtin_amdgcn_s_setprio(0);
    }
#pragma unroll
    for (int mf = 0; mf < 2; ++mf) {
#pragma unroll
        for (int r = 0; r < 4; ++r) {
            const int row = n0 + wr * 32 + mf * 16 + lg * 4 + r;
#pragma unroll
            for (int nf = 0; nf < 4; ++nf) {
                const int col = j0 + wc * 64 + nf * 16 + li;
                C[(size_t)row * N + col] = f2bf(acc[mf][nf][r]);
            }
        }
    }
}

// ---------------------------------------------------------------- MFMA flash attention, K-split x4
// ROUND-14 PROVEN STRUCTURE (unchanged): BQ=128, 8 waves x 16 q-rows; swapped QK^T;
// defer-max (THR=8); XOR-swizzled K/V LDS; launch_bounds(512,2).
__global__ __launch_bounds__(512, 2) void attn_mfma(const unsigned short* __restrict__ Qb,
                                                    const unsigned short* __restrict__ Kb,
                                                    const unsigned short* __restrict__ Vtb,
                                                    const int* __restrict__ prows,
                                                    const int* __restrict__ pcols,
                                                    const float* __restrict__ dist_bias,
                                                    unsigned short* __restrict__ Opart,
                                                    float* __restrict__ Mp,
                                                    float* __restrict__ Lp) {
    const int h  = blockIdx.y;
    const int n0 = blockIdx.x * BQ;
    const int sp = blockIdx.z;
    __shared__ unsigned short Ks[BK * HDIM];        // [64][128] XOR-swizzled
    __shared__ unsigned short Vts[HDIM * BK];       // [128][64] XOR-swizzled
    __shared__ unsigned short Ps[BQ][68];           // +4 pad
    __shared__ unsigned short biasTb[3043];
    __shared__ int krs[BK], kcs[BK];

    const int t    = threadIdx.x;
    const int lane = t & 63;
    const int lg   = lane >> 4;
    const int li   = lane & 15;
    const int qbase = (t >> 6) * 16;   // 8 waves x 16 q-rows

    for (int idx = t; idx < 3043; idx += 512) {
        float d  = sqrtf((float)idx);
        int bin  = (int)(log1pf(d) * (31.0f / 4.0529789877f));
        bin = bin > 31 ? 31 : bin;
        biasTb[idx] = f2bf(dist_bias[h * NBINS + bin]);
    }

    bf16x8 qf[4];
    {
        const unsigned short* qptr = &Qb[(size_t)(n0 + qbase + li) * QKSTR + h * HDIM];
#pragma unroll
        for (int kc = 0; kc < 4; ++kc)
            qf[kc] = *(const bf16x8*)&qptr[kc * 32 + lg * 8];
    }
    const int qrL = prows[n0 + qbase + li];
    const int qcL = pcols[n0 + qbase + li];

    float m_ = -1e30f;
    float l_ = 0.f;
    f32x4 accO[8];
#pragma unroll
    for (int dt = 0; dt < 8; ++dt) accO[dt] = (f32x4){0.f, 0.f, 0.f, 0.f};

    u16x8 kreg[2], vreg[2];
    int krreg = 0, kcreg = 0;
    const int ktr = t >> 4, kch = (t & 15) * 8;
    const int vtr = t >> 3, vch = (t & 7) * 8;

    const int kwofs0 = (ktr * 128 + kch) * 2;
    const int vwofs0 = (vtr * 64 + vch) * 2;

    int m0 = sp * KV_PER_SPLIT;
    {
#pragma unroll
        for (int i = 0; i < 2; ++i)
            kreg[i] = *(const u16x8*)&Kb[(size_t)(m0 + ktr + i * 32) * QKSTR + h * HDIM + kch];
#pragma unroll
        for (int i = 0; i < 2; ++i)
            vreg[i] = *(const u16x8*)&Vtb[(size_t)(h * HDIM + vtr + i * 64) * N_TOK + m0 + vch];
        if (t < BK) { krreg = prows[m0 + t]; kcreg = pcols[m0 + t]; }
    }

    for (int kb = 0; kb < KV_PER_SPLIT / BK; ++kb, m0 += BK) {
        __syncthreads();
#pragma unroll
        for (int i = 0; i < 2; ++i) {
            int ofs = (kwofs0 + i * 32 * 256) ^ ((ktr & 7) << 4);
            *(u16x8*)((char*)Ks + ofs) = kreg[i];
        }
#pragma unroll
        for (int i = 0; i < 2; ++i) {
            int ofs = (vwofs0 + i * 64 * 128) ^ ((vtr & 7) << 4);
            *(u16x8*)((char*)Vts + ofs) = vreg[i];
        }
        if (t < BK) { krs[t] = krreg; kcs[t] = kcreg; }
        __syncthreads();

        if (kb + 1 < KV_PER_SPLIT / BK) {
            const int m1 = m0 + BK;
#pragma unroll
            for (int i = 0; i < 2; ++i)
                kreg[i] = *(const u16x8*)&Kb[(size_t)(m1 + ktr + i * 32) * QKSTR + h * HDIM + kch];
#pragma unroll
            for (int i = 0; i < 2; ++i)
                vreg[i] = *(const u16x8*)&Vtb[(size_t)(h * HDIM + vtr + i * 64) * N_TOK + m1 + vch];
            if (t < BK) { krreg = prows[m1 + t]; kcreg = pcols[m1 + t]; }
        }

        // ---- S^T = K Q^T
        f32x4 s[4];
        __builtin_amdgcn_s_setprio(1);
#pragma unroll
        for (int jt = 0; jt < 4; ++jt) {
            f32x4 acc = {0.f, 0.f, 0.f, 0.f};
#pragma unroll
            for (int kc = 0; kc < 4; ++kc) {
                int ofs = (((jt * 16 + li) * 128 + kc * 32 + lg * 8) * 2) ^ ((li & 7) << 4);
                bf16x8 kf = *(const bf16x8*)((const char*)Ks + ofs);
                acc = __builtin_amdgcn_mfma_f32_16x16x32_bf16(kf, qf[kc], acc, 0, 0, 0);
            }
            s[jt] = acc;
        }
        __builtin_amdgcn_s_setprio(0);

        // ---- bias
        float p[4][4];
#pragma unroll
        for (int jt = 0; jt < 4; ++jt) {
#pragma unroll
            for (int r = 0; r < 4; ++r) {
                int k  = jt * 16 + lg * 4 + r;
                int dr = qrL - krs[k], dc = qcL - kcs[k];
                p[jt][r] = s[jt][r] + bf2f(biasTb[dr * dr + dc * dc]);
            }
        }

        // ---- row max: tree + 2 shfl
        float t0 = fmaxf(fmaxf(p[0][0], p[0][1]), fmaxf(p[0][2], p[0][3]));
        float t1 = fmaxf(fmaxf(p[1][0], p[1][1]), fmaxf(p[1][2], p[1][3]));
        float t2 = fmaxf(fmaxf(p[2][0], p[2][1]), fmaxf(p[2][2], p[2][3]));
        float t3 = fmaxf(fmaxf(p[3][0], p[3][1]), fmaxf(p[3][2], p[3][3]));
        float pmax = fmaxf(fmaxf(t0, t1), fmaxf(t2, t3));
        pmax = fmaxf(pmax, __shfl_xor(pmax, 16));
        pmax = fmaxf(pmax, __shfl_xor(pmax, 32));

        // ---- defer-max (THR=8)
        if (!__all(pmax <= m_ + 8.0f)) {
            float mnew  = fmaxf(m_, pmax);
            float alpha = __expf(m_ - mnew);
            m_ = mnew;
            l_ *= alpha;
            float aq[4];
#pragma unroll
            for (int r = 0; r < 4; ++r)
                aq[r] = __shfl(alpha, (lane & 48) | (lg * 4 + r));
#pragma unroll
            for (int dt = 0; dt < 8; ++dt)
#pragma unroll
                for (int r = 0; r < 4; ++r) accO[dt][r] *= aq[r];
        }

        // ---- exp + row sum
        float rs = 0.f;
#pragma unroll
        for (int jt = 0; jt < 4; ++jt)
#pragma unroll
            for (int r = 0; r < 4; ++r) { p[jt][r] = __expf(p[jt][r] - m_); rs += p[jt][r]; }
        rs += __shfl_xor(rs, 16);
        rs += __shfl_xor(rs, 32);
        l_ += rs;

        // ---- P -> LDS (native bf16 cvt)
#pragma unroll
        for (int jt = 0; jt < 4; ++jt) {
            u16x4 w;
#pragma unroll
            for (int r = 0; r < 4; ++r) w[r] = f2bf_hw(p[jt][r]);
            *(u16x4*)&Ps[qbase + li][jt * 16 + lg * 4] = w;
        }

        // ---- O += P V
        bf16x8 pf0 = *(const bf16x8*)&Ps[qbase + li][lg * 8];
        bf16x8 pf1 = *(const bf16x8*)&Ps[qbase + li][32 + lg * 8];
        __builtin_amdgcn_s_setprio(1);
#pragma unroll
        for (int dt = 0; dt < 8; ++dt) {
            int ofs0 = (((dt * 16 + li) * 64 + lg * 8) * 2) ^ ((li & 7) << 4);
            bf16x8 vf0 = *(const bf16x8*)((const char*)Vts + ofs0);
            bf16x8 vf1 = *(const bf16x8*)((const char*)Vts + (ofs0 ^ 64));
            accO[dt] = __builtin_amdgcn_mfma_f32_16x16x32_bf16(pf0, vf0, accO[dt], 0, 0, 0);
            accO[dt] = __builtin_amdgcn_mfma_f32_16x16x32_bf16(pf1, vf1, accO[dt], 0, 0, 0);
        }
        __builtin_amdgcn_s_setprio(0);
    }

    // ---- epilogue
    float linv[4];
#pragma unroll
    for (int r = 0; r < 4; ++r)
        linv[r] = __shfl(l_, (lane & 48) | (lg * 4 + r));
#pragma unroll
    for (int r = 0; r < 4; ++r) {
        float inv = 1.0f / linv[r];
        int row = n0 + qbase + lg * 4 + r;
#pragma unroll
        for (int dt = 0; dt < 8; ++dt)
            Opart[(size_t)sp * N_TOK * DMODEL + (size_t)row * DMODEL + h * HDIM + dt * 16 + li] =
                f2bf(accO[dt][r] * inv);
    }
    if (lane < 16) {
        int row = n0 + qbase + lane;
        Mp[((size_t)sp * NHEAD + h) * N_TOK + row] = m_;
        Lp[((size_t)sp * NHEAD + h) * N_TOK + row] = l_;
    }
}

// ---------------------------------------------------------------- LN + gated residual (bf16 o input)
__global__ __launch_bounds__(256) void final_kernel(const unsigned short* __restrict__ o,
                                                    const float* __restrict__ vh,
                                                    const float* __restrict__ lnw,
                                                    const float* __restrict__ lnb,
                                                    const float* __restrict__ gparam,
                                                    float* __restrict__ out) {
    int n = blockIdx.x, t = threadIdx.x;
    size_t base = (size_t)n * DMODEL;
    float x0 = bf2f(o[base + t]), x1 = bf2f(o[base + t + 256]);
    __shared__ float red[4];
    float v = x0 + x1;
#pragma unroll
    for (int off = 32; off > 0; off >>= 1) v += __shfl_down(v, off, 64);
    if ((t & 63) == 0) red[t >> 6] = v;
    __syncthreads();
    float mu = (red[0] + red[1] + red[2] + red[3]) * (1.0f / 512.0f);
    __syncthreads();
    float d0 = x0 - mu, d1 = x1 - mu;
    v = d0 * d0 + d1 * d1;
#pragma unroll
    for (int off = 32; off > 0; off >>= 1) v += __shfl_down(v, off, 64);
    if ((t & 63) == 0) red[t >> 6] = v;
    __syncthreads();
    float var  = (red[0] + red[1] + red[2] + red[3]) * (1.0f / 512.0f);
    float rstd = rsqrtf(var + 1e-5f);
    float gamma = log1pf(expf(gparam[0]));
    out[base + t]       = vh[base + t]       + gamma * (d0 * rstd * lnw[t]       + lnb[t]);
    out[base + t + 256] = vh[base + t + 256] + gamma * (d1 * rstd * lnw[t + 256] + lnb[t + 256]);
}

// ---------------------------------------------------------------- launch
extern "C" void kernel_launch(void* const* d_in, const int* in_sizes, int n_in,
                              void* d_out, int out_size, void* d_ws, size_t ws_size,
                              hipStream_t stream) {
    const float* vision_h  = (const float*)d_in[0];
    const int*   prows     = (const int*)d_in[1];
    const int*   pcols     = (const int*)d_in[2];
    const float* pos_w     = (const float*)d_in[3];
    const float* q_w       = (const float*)d_in[4];
    const float* k_w       = (const float*)d_in[5];
    const float* v_w       = (const float*)d_in[6];
    const float* out_w     = (const float*)d_in[7];
    const float* dist_bias = (const float*)d_in[8];
    const float* gamma_p   = (const float*)d_in[9];
    const float* ln_w      = (const float*)d_in[10];
    const float* ln_b      = (const float*)d_in[11];
    float* out = (float*)d_out;
    char* base = (char*)d_ws;

    const size_t MB = 1024 * 1024;
    unsigned short* vh_bf   = (unsigned short*)(base + 4  * MB);
    unsigned short* hpos_bf = (unsigned short*)(base + 8  * MB);
    unsigned short* Opart   = (unsigned short*)(base + 0);        // 16MB, after vh/hpos dead
    unsigned short* QKb     = (unsigned short*)(base + 16 * MB);  // 8MB fused Q|K [4096][1024]
    unsigned short* Vtb     = (unsigned short*)(base + 24 * MB);  // 4MB
    unsigned short* ob_bf   = (unsigned short*)(base + 28 * MB);  // 4MB (old attn_bf slot; Opart stays live)
    float*          Mp      = (float*)(base + 32 * MB);           // 256KB
    float*          Lp      = (float*)(base + 32 * MB + 262144);  // 256KB
    unsigned short* wbf     = (unsigned short*)(base + 32 * MB + 524288);  // 2.5MB
    float*          contrib = (float*)(base + 35 * MB);           // 80x512 f32 = 160KB

    unsigned short* w_q   = wbf + 1 * DMODEL * DMODEL;  // w_q||w_k contiguous -> fused B [1024][512]
    unsigned short* w_v   = wbf + 3 * DMODEL * DMODEL;
    unsigned short* w_o   = wbf + 4 * DMODEL * DMODEL;

    const float qscale = 0.08838834764831845f;  // 1/sqrt(128)

    prep2_kernel<<<1600, 256, 0, stream>>>(pos_w, q_w, k_w, v_w, out_w, pos_w, wbf, contrib);
    hpos_kernel<<<N_TOK, 256, 0, stream>>>(prows, pcols, vision_h, contrib, vh_bf, hpos_bf);
    // fused [Q|K] = h_pos @ [w_q;w_k]^T  (cols<512 scaled by qscale)
    gemm_mfma<false, true ><<<dim3(64, 8), 256, 0, stream>>>(hpos_bf, w_q, nullptr, QKb,
                                                             N_TOK, 1024, DMODEL, qscale, 1.0f);
    // Vt = v_w @ vision_h^T
    gemm_mfma<false, true ><<<dim3(8, 32), 256, 0, stream>>>(w_v, vh_bf, nullptr, Vtb,
                                                             DMODEL, N_TOK, DMODEL, 1.0f, 1.0f);
    attn_mfma<<<dim3(N_TOK / BQ, NHEAD, NSPLIT), 512, 0, stream>>>(QKb, QKb + 512, Vtb, prows, pcols,
                                                                   dist_bias, Opart, Mp, Lp);
    // o = combine(Opart) @ out_w^T, combine fused into A-staging (bf16 out)
    gemm_out<<<dim3(64, 4), 256, 0, stream>>>(Opart, Mp, Lp, w_o, ob_bf);
    final_kernel<<<N_TOK, 256, 0, stream>>>(ob_bf, vision_h, ln_w, ln_b, gamma_p, out);
}